// Round 1
// 472.010 us; speedup vs baseline: 1.0953x; 1.0953x over previous
//
#include <hip/hip_runtime.h>
#include <math.h>

#define NB 8192
#define H 1024
#define HH 512
#define NEXP 16
#define NTILES 272          // max sum of per-expert ceil(cnt/32)
#define AMBIG_THR 1e-3f     // ~50 sigma of split-bf16 logit error

// MFMA 16x16x32 bf16 fragments
typedef __attribute__((ext_vector_type(8))) short bfrag;
typedef __attribute__((ext_vector_type(4))) float f4;

__device__ __forceinline__ f4 MF(bfrag a, bfrag b, f4 c) {
    return __builtin_amdgcn_mfma_f32_16x16x32_bf16(a, b, c, 0, 0, 0);
}
__device__ __forceinline__ unsigned short f2bf(float f) {  // RNE fp32->bf16
    unsigned u = __float_as_uint(f);
    u += 0x7fff + ((u >> 16) & 1);
    return (unsigned short)(u >> 16);
}
__device__ __forceinline__ float bf2f(unsigned short h) {
    return __uint_as_float((unsigned)h << 16);
}

// async global->LDS, 16B per lane; LDS dest is wave-uniform base + lane*16
typedef __attribute__((address_space(1))) const unsigned GAS;
typedef __attribute__((address_space(3))) unsigned LAS;
__device__ __forceinline__ void gld16(const void* g, void* l) {
    __builtin_amdgcn_global_load_lds((GAS*)g, (LAS*)l, 16, 0, 0);
}

// fused split-conversion: q (8192 blocks), w1 (512), w3 (8); block 0 zeroes counters
__global__ __launch_bounds__(256) void cvtA_kernel(
    const float* __restrict__ q, const float* __restrict__ w1, const float* __restrict__ w3,
    unsigned short* __restrict__ qhi, unsigned short* __restrict__ qlo,
    unsigned short* __restrict__ w1hi, unsigned short* __restrict__ w1lo,
    unsigned short* __restrict__ w3hi, unsigned short* __restrict__ w3lo,
    int* __restrict__ counts, int* __restrict__ ambig_cnt)
{
    const int b = blockIdx.x, t = threadIdx.x;
    if (b == 0) {
        if (t < NEXP) counts[t] = 0;
        if (t == NEXP) ambig_cnt[0] = 0;
    }
    const float* src; unsigned short *hi, *lo; int i;
    if (b < 8192)      { src = q;  hi = qhi;  lo = qlo;  i = b * 256 + t; }
    else if (b < 8704) { src = w1; hi = w1hi; lo = w1lo; i = (b - 8192) * 256 + t; }
    else               { src = w3; hi = w3hi; lo = w3lo; i = (b - 8704) * 256 + t; }
    float4 v = ((const float4*)src)[i];
    ushort4 h, l;
    h.x = f2bf(v.x); l.x = f2bf(v.x - bf2f(h.x));
    h.y = f2bf(v.y); l.y = f2bf(v.y - bf2f(h.y));
    h.z = f2bf(v.z); l.z = f2bf(v.z - bf2f(h.z));
    h.w = f2bf(v.w); l.w = f2bf(v.w - bf2f(h.w));
    ((ushort4*)hi)[i] = h;
    ((ushort4*)lo)[i] = l;
}

// fused plain conversion: exp_w1 (8192 blocks), exp_w2 (8192 blocks)
__global__ __launch_bounds__(256) void cvtB_kernel(
    const float* __restrict__ ew1, const float* __restrict__ ew2,
    unsigned short* __restrict__ d1, unsigned short* __restrict__ d2)
{
    const int b = blockIdx.x, t = threadIdx.x;
    const float* src; unsigned short* dst; int i;
    if (b < 8192) { src = ew1; dst = d1; i = b * 256 + t; }
    else          { src = ew2; dst = d2; i = (b - 8192) * 256 + t; }
    float4 v = ((const float4*)src)[i];
    ushort4 h;
    h.x = f2bf(v.x); h.y = f2bf(v.y); h.z = f2bf(v.z); h.w = f2bf(v.w);
    ((ushort4*)dst)[i] = h;
}

// ---- gating GEMM1 (split 3-term): x1 = relu(q @ w1^T + b1), stored hi/lo ----
// LDS-staged multi-wave rewrite: 128x64 tile, BK=32, 4 waves (each 32 rows x 64 cols),
// double-buffered global_load_lds(16B) staging with XOR-swizzled sources.
// grid (64, 8), block 256.
__global__ __launch_bounds__(256) void g1_kernel(
    const unsigned short* __restrict__ qhi, const unsigned short* __restrict__ qlo,
    const unsigned short* __restrict__ w1hi, const unsigned short* __restrict__ w1lo,
    const float* __restrict__ b1,
    unsigned short* __restrict__ x1hi, unsigned short* __restrict__ x1lo)
{
    __shared__ unsigned short Ah[2][128][32];
    __shared__ unsigned short Al[2][128][32];
    __shared__ unsigned short Bh[2][64][32];
    __shared__ unsigned short Bl[2][64][32];

    const int t = threadIdx.x, w = t >> 6, lane = t & 63;
    const int quad = lane >> 4, l16 = lane & 15;
    const int rowA0 = blockIdx.x * 128;
    const int colB0 = blockIdx.y * 64;
    const int rl = lane >> 2, sl = lane & 3;   // staging: 16 rows x 4 slots per 1KB chunk

    // Per-wave staging plan: 6 chunks each, chunk ids c = w + 4*j, j=0..5.
    // c 0-7: Ah rows [c*16..+16) ; 8-15: Al ; 16-19: Bh ; 20-23: Bl.
    // LDS dest is linear (base + lane*16); source k-slot is pre-swizzled by row&3
    // so that the swizzled ds_read below retrieves the correct fragment (rule: both-sides swizzle).
    const unsigned short* gsrc[6];
    unsigned short* lbase[6];
    int bstr[6];
    #pragma unroll
    for (int j = 0; j < 6; ++j) {
        int c = w + j * 4;
        int rloc; const unsigned short* s; unsigned short* d; int str;
        if (c < 8)       { rloc = c * 16 + rl;        s = qhi  + (size_t)(rowA0 + rloc) * H; d = &Ah[0][c * 16][0];        str = 128 * 32; }
        else if (c < 16) { rloc = (c - 8) * 16 + rl;  s = qlo  + (size_t)(rowA0 + rloc) * H; d = &Al[0][(c - 8) * 16][0];  str = 128 * 32; }
        else if (c < 20) { rloc = (c - 16) * 16 + rl; s = w1hi + (size_t)(colB0 + rloc) * H; d = &Bh[0][(c - 16) * 16][0]; str = 64 * 32; }
        else             { rloc = (c - 20) * 16 + rl; s = w1lo + (size_t)(colB0 + rloc) * H; d = &Bl[0][(c - 20) * 16][0]; str = 64 * 32; }
        gsrc[j]  = s + (sl ^ (rloc & 3)) * 8;   // pre-swizzled k-slot in the source
        lbase[j] = d;
        bstr[j]  = str;
    }

    const f4 z4 = {0.f, 0.f, 0.f, 0.f};
    f4 acc[2][4] = {{z4, z4, z4, z4}, {z4, z4, z4, z4}};
    const int sA = (quad ^ (l16 & 3)) * 8;     // swizzled read slot (row&3 == l16&3 here)
    const int ra0 = w * 32 + l16, ra1 = ra0 + 16;

    auto STAGE = [&](int buf, int kt) {
        #pragma unroll
        for (int j = 0; j < 6; ++j)
            gld16(gsrc[j] + kt * 32, lbase[j] + buf * bstr[j]);
    };
    auto COMPUTE = [&](int buf) {
        bfrag ah0 = *(const bfrag*)&Ah[buf][ra0][sA];
        bfrag al0 = *(const bfrag*)&Al[buf][ra0][sA];
        bfrag ah1 = *(const bfrag*)&Ah[buf][ra1][sA];
        bfrag al1 = *(const bfrag*)&Al[buf][ra1][sA];
        #pragma unroll
        for (int cb = 0; cb < 4; ++cb) {
            bfrag bh = *(const bfrag*)&Bh[buf][cb * 16 + l16][sA];
            bfrag bl = *(const bfrag*)&Bl[buf][cb * 16 + l16][sA];
            acc[0][cb] = MF(al0, bh, MF(ah0, bl, MF(ah0, bh, acc[0][cb])));
            acc[1][cb] = MF(al1, bh, MF(ah1, bl, MF(ah1, bh, acc[1][cb])));
        }
    };

    STAGE(0, 0);
    __syncthreads();
    int cur = 0;
    for (int kt = 1; kt < 32; ++kt) {
        STAGE(cur ^ 1, kt);     // prefetch next K-tile while computing current
        COMPUTE(cur);
        __syncthreads();        // compiler drains vmcnt+lgkmcnt here (m97 structure)
        cur ^= 1;
    }
    COMPUTE(cur);

    const int row0 = rowA0 + w * 32;
    #pragma unroll
    for (int cb = 0; cb < 4; ++cb) {
        int col = colB0 + cb * 16 + l16;
        float bias = b1[col];
        #pragma unroll
        for (int rb = 0; rb < 2; ++rb)
            #pragma unroll
            for (int i = 0; i < 4; ++i) {
                int row = rb * 16 + quad * 4 + i;
                float v = fmaxf(acc[rb][cb][i] + bias, 0.f);
                unsigned short hh = f2bf(v);
                size_t idx = (size_t)(row0 + row) * HH + col;
                x1hi[idx] = hh;
                x1lo[idx] = f2bf(v - bf2f(hh));
            }
    }
}

// ---- logits (split 3-term) + argmax + gate + counts + ambiguity flag ----
__global__ __launch_bounds__(256) void logits_kernel(
    const unsigned short* __restrict__ x1hi, const unsigned short* __restrict__ x1lo,
    const unsigned short* __restrict__ w3hi, const unsigned short* __restrict__ w3lo,
    const float* __restrict__ b3,
    int* __restrict__ top1, float* __restrict__ gval, int* __restrict__ counts,
    int* __restrict__ ambig_rows, int* __restrict__ ambig_cnt)
{
    __shared__ float lgp[4][32][NEXP];
    const int t = threadIdx.x, wave = t >> 6, lane = t & 63;
    const int quad = lane >> 4, l16 = lane & 15;
    const int row0 = blockIdx.x * 32;
    const f4 z4 = {0.f, 0.f, 0.f, 0.f};

    f4 l0 = z4, l1 = z4;
    const size_t ar0 = (size_t)(row0 + l16) * HH + quad * 8;
    const size_t ar1 = ar0 + (size_t)16 * HH;
    const size_t br = (size_t)l16 * HH + quad * 8;
    #pragma unroll
    for (int ks = 0; ks < 4; ++ks) {
        int kk = wave * 128 + ks * 32;
        bfrag ah0 = *(const bfrag*)(x1hi + ar0 + kk);
        bfrag al0 = *(const bfrag*)(x1lo + ar0 + kk);
        bfrag ah1 = *(const bfrag*)(x1hi + ar1 + kk);
        bfrag al1 = *(const bfrag*)(x1lo + ar1 + kk);
        bfrag bh  = *(const bfrag*)(w3hi + br + kk);
        bfrag bl  = *(const bfrag*)(w3lo + br + kk);
        l0 = MF(al0, bh, MF(ah0, bl, MF(ah0, bh, l0)));
        l1 = MF(al1, bh, MF(ah1, bl, MF(ah1, bh, l1)));
    }
    #pragma unroll
    for (int i = 0; i < 4; ++i) {
        lgp[wave][quad * 4 + i][l16] = l0[i];
        lgp[wave][16 + quad * 4 + i][l16] = l1[i];
    }
    __syncthreads();

    if (t < 32) {
        float lg[NEXP];
        #pragma unroll
        for (int m = 0; m < NEXP; ++m)
            lg[m] = lgp[0][t][m] + lgp[1][t][m] + lgp[2][t][m] + lgp[3][t][m] + b3[m];
        float best = lg[0], second = -3.4e38f; int bi = 0;
        #pragma unroll
        for (int m = 1; m < NEXP; ++m) {
            float v = lg[m];
            if (v > best) { second = best; best = v; bi = m; }
            else if (v > second) second = v;
        }
        float se = 0.f;
        #pragma unroll
        for (int m = 0; m < NEXP; ++m) se += expf(lg[m] - best);
        int grow = row0 + t;
        top1[grow] = bi;
        gval[grow] = 1.f / se;
        atomicAdd(&counts[bi], 1);
        if (best - second < AMBIG_THR) {
            int pos = atomicAdd(ambig_cnt, 1);
            if (pos < NB) ambig_rows[pos] = grow;
        }
    }
}

// ---- exact fp32 recompute for ambiguous rows (expected ~2-5 rows) ----
__global__ __launch_bounds__(256) void fixup_kernel(
    const float* __restrict__ q, const float* __restrict__ w1, const float* __restrict__ b1,
    const float* __restrict__ w3, const float* __restrict__ b3,
    const int* __restrict__ ambig_rows, const int* __restrict__ ambig_cnt,
    int* __restrict__ top1, float* __restrict__ gval, int* __restrict__ counts)
{
    __shared__ __align__(16) float qrow[H];
    __shared__ __align__(16) float x1[HH];
    __shared__ float lgs[NEXP];
    const int t = threadIdx.x, wv = t >> 6, ln = t & 63;
    int nn = *ambig_cnt; if (nn > NB) nn = NB;
    for (int ii = blockIdx.x; ii < nn; ii += gridDim.x) {
        int row = ambig_rows[ii];
        ((float4*)qrow)[t] = ((const float4*)(q + (size_t)row * H))[t];
        __syncthreads();
        for (int c = wv * 2; c < HH; c += 8) {
            const float4* w0 = (const float4*)(w1 + (size_t)c * H);
            const float4* w1r = (const float4*)(w1 + (size_t)(c + 1) * H);
            const float4* qv = (const float4*)qrow;
            float s0 = 0.f, s1 = 0.f;
            #pragma unroll
            for (int j = 0; j < 4; ++j) {
                float4 a = qv[j * 64 + ln];
                float4 b0 = w0[j * 64 + ln];
                float4 b1v = w1r[j * 64 + ln];
                s0 += a.x * b0.x + a.y * b0.y + a.z * b0.z + a.w * b0.w;
                s1 += a.x * b1v.x + a.y * b1v.y + a.z * b1v.z + a.w * b1v.w;
            }
            #pragma unroll
            for (int off = 32; off; off >>= 1) {
                s0 += __shfl_xor(s0, off, 64);
                s1 += __shfl_xor(s1, off, 64);
            }
            if (ln == 0) {
                x1[c]     = fmaxf(s0 + b1[c], 0.f);
                x1[c + 1] = fmaxf(s1 + b1[c + 1], 0.f);
            }
        }
        __syncthreads();
        for (int m = wv; m < NEXP; m += 4) {
            const float4* wr = (const float4*)(w3 + (size_t)m * HH);
            const float4* xv = (const float4*)x1;
            float s = 0.f;
            #pragma unroll
            for (int j = 0; j < 2; ++j) {
                float4 a = xv[j * 64 + ln];
                float4 b = wr[j * 64 + ln];
                s += a.x * b.x + a.y * b.y + a.z * b.z + a.w * b.w;
            }
            #pragma unroll
            for (int off = 32; off; off >>= 1) s += __shfl_xor(s, off, 64);
            if (ln == 0) lgs[m] = s + b3[m];
        }
        __syncthreads();
        if (t == 0) {
            float best = lgs[0]; int bi = 0;
            #pragma unroll
            for (int m = 1; m < NEXP; ++m) if (lgs[m] > best) { best = lgs[m]; bi = m; }
            float se = 0.f;
            #pragma unroll
            for (int m = 0; m < NEXP; ++m) se += expf(lgs[m] - best);
            int old = top1[row];
            if (bi != old) {
                atomicSub(&counts[old], 1);
                atomicAdd(&counts[bi], 1);
                top1[row] = bi;
            }
            gval[row] = 1.f / se;
        }
        __syncthreads();
    }
}

// offsets + tile map
__global__ __launch_bounds__(64) void offsets_kernel(
    const int* __restrict__ counts, int* __restrict__ offsets, int* __restrict__ bpos,
    int* __restrict__ tm_e, int* __restrict__ tm_p, int* __restrict__ tm_end)
{
    if (threadIdx.x == 0) {
        int run = 0;
        for (int e = 0; e < NEXP; ++e) { offsets[e] = run; bpos[e] = run; run += counts[e]; }
        int tile = 0;
        for (int e = 0; e < NEXP; ++e) {
            int beg = offsets[e], end = beg + counts[e];
            for (int p = beg; p < end; p += 32) {
                tm_e[tile] = e; tm_p[tile] = p; tm_end[tile] = end; ++tile;
            }
        }
        for (; tile < NTILES; ++tile) tm_e[tile] = -1;
    }
}

__global__ __launch_bounds__(256) void scatter_kernel(
    const int* __restrict__ top1, int* __restrict__ bpos, int* __restrict__ brows)
{
    int b = blockIdx.x * 256 + threadIdx.x;
    int e = top1[b];
    int pos = atomicAdd(&bpos[e], 1);
    brows[pos] = b;
}

// ---- expert GEMM1: h[pos][512] = relu(q[row] @ w1[e]^T + b1[e]) ----
// single-wave; wave tile 32 x 64; grid (NTILES, 8).
__global__ __launch_bounds__(64) void exp1_kernel(
    const unsigned short* __restrict__ qb, const unsigned short* __restrict__ ew1b,
    const float* __restrict__ eb1,
    const int* __restrict__ tm_e, const int* __restrict__ tm_p, const int* __restrict__ tm_end,
    const int* __restrict__ brows, unsigned short* __restrict__ h)
{
    const int e = tm_e[blockIdx.x];
    if (e < 0) return;
    const int p0 = tm_p[blockIdx.x], end = tm_end[blockIdx.x];
    const int lane = threadIdx.x & 63, quad = lane >> 4, l16 = lane & 15;

    int pa = p0 + l16;      if (pa >= end) pa = end - 1;
    int pb = p0 + 16 + l16; if (pb >= end) pb = end - 1;
    const int r0 = brows[pa], r1 = brows[pb];

    const int c0 = blockIdx.y * 64;
    const unsigned short* w1p = ew1b + (size_t)e * HH * H;
    const f4 z4 = {0.f, 0.f, 0.f, 0.f};
    f4 acc[2][4] = {{z4, z4, z4, z4}, {z4, z4, z4, z4}};

    const size_t ar0 = (size_t)r0 * H + quad * 8;
    const size_t ar1 = (size_t)r1 * H + quad * 8;
    size_t br[4];
    #pragma unroll
    for (int cb = 0; cb < 4; ++cb) br[cb] = (size_t)(c0 + cb * 16 + l16) * H + quad * 8;

    bfrag a0 = *(const bfrag*)(qb + ar0);
    bfrag a1 = *(const bfrag*)(qb + ar1);
    bfrag bb[4];
    #pragma unroll
    for (int cb = 0; cb < 4; ++cb) bb[cb] = *(const bfrag*)(w1p + br[cb]);
    #pragma unroll 2
    for (int kk = 32; kk <= H - 32; kk += 32) {
        bfrag na0 = *(const bfrag*)(qb + ar0 + kk);
        bfrag na1 = *(const bfrag*)(qb + ar1 + kk);
        bfrag nbb[4];
        #pragma unroll
        for (int cb = 0; cb < 4; ++cb) nbb[cb] = *(const bfrag*)(w1p + br[cb] + kk);
        #pragma unroll
        for (int cb = 0; cb < 4; ++cb) {
            acc[0][cb] = MF(a0, bb[cb], acc[0][cb]);
            acc[1][cb] = MF(a1, bb[cb], acc[1][cb]);
        }
        a0 = na0; a1 = na1;
        #pragma unroll
        for (int cb = 0; cb < 4; ++cb) bb[cb] = nbb[cb];
    }
    #pragma unroll
    for (int cb = 0; cb < 4; ++cb) {
        acc[0][cb] = MF(a0, bb[cb], acc[0][cb]);
        acc[1][cb] = MF(a1, bb[cb], acc[1][cb]);
    }

    #pragma unroll
    for (int cb = 0; cb < 4; ++cb) {
        int col = c0 + cb * 16 + l16;
        float bias = eb1[e * HH + col];
        #pragma unroll
        for (int rb = 0; rb < 2; ++rb)
            #pragma unroll
            for (int i = 0; i < 4; ++i) {
                int row = rb * 16 + quad * 4 + i;
                if (p0 + row < end)
                    h[(size_t)(p0 + row) * HH + col] = f2bf(fmaxf(acc[rb][cb][i] + bias, 0.f));
            }
    }
}

// ---- expert GEMM2: v = h @ w2[e]^T + b2[e]; psum[row][cg] = partial sum v^2 ----
// single-wave; wave tile 32 x 64; grid (NTILES, 16).
__global__ __launch_bounds__(64) void exp2_kernel(
    const unsigned short* __restrict__ h, const unsigned short* __restrict__ ew2b,
    const float* __restrict__ eb2,
    const int* __restrict__ tm_e, const int* __restrict__ tm_p, const int* __restrict__ tm_end,
    const int* __restrict__ brows,
    float* __restrict__ vout, float* __restrict__ psum)
{
    const int e = tm_e[blockIdx.x];
    if (e < 0) return;
    const int p0 = tm_p[blockIdx.x], end = tm_end[blockIdx.x];
    const int lane = threadIdx.x & 63, quad = lane >> 4, l16 = lane & 15;
    const int cg = blockIdx.y;

    int pa = p0 + l16;      if (pa >= end) pa = end - 1;
    int pb = p0 + 16 + l16; if (pb >= end) pb = end - 1;

    const int c0 = cg * 64;
    const unsigned short* w2p = ew2b + (size_t)e * H * HH;
    const f4 z4 = {0.f, 0.f, 0.f, 0.f};
    f4 acc[2][4] = {{z4, z4, z4, z4}, {z4, z4, z4, z4}};

    const size_t ar0 = (size_t)pa * HH + quad * 8;
    const size_t ar1 = (size_t)pb * HH + quad * 8;
    size_t br[4];
    #pragma unroll
    for (int cb = 0; cb < 4; ++cb) br[cb] = (size_t)(c0 + cb * 16 + l16) * HH + quad * 8;

    bfrag a0 = *(const bfrag*)(h + ar0);
    bfrag a1 = *(const bfrag*)(h + ar1);
    bfrag bb[4];
    #pragma unroll
    for (int cb = 0; cb < 4; ++cb) bb[cb] = *(const bfrag*)(w2p + br[cb]);
    #pragma unroll 2
    for (int kk = 32; kk <= HH - 32; kk += 32) {
        bfrag na0 = *(const bfrag*)(h + ar0 + kk);
        bfrag na1 = *(const bfrag*)(h + ar1 + kk);
        bfrag nbb[4];
        #pragma unroll
        for (int cb = 0; cb < 4; ++cb) nbb[cb] = *(const bfrag*)(w2p + br[cb] + kk);
        #pragma unroll
        for (int cb = 0; cb < 4; ++cb) {
            acc[0][cb] = MF(a0, bb[cb], acc[0][cb]);
            acc[1][cb] = MF(a1, bb[cb], acc[1][cb]);
        }
        a0 = na0; a1 = na1;
        #pragma unroll
        for (int cb = 0; cb < 4; ++cb) bb[cb] = nbb[cb];
    }
    #pragma unroll
    for (int cb = 0; cb < 4; ++cb) {
        acc[0][cb] = MF(a0, bb[cb], acc[0][cb]);
        acc[1][cb] = MF(a1, bb[cb], acc[1][cb]);
    }

    // bias + v-write + per-row sum(v^2)
    float rs0[4] = {0.f, 0.f, 0.f, 0.f}, rs1[4] = {0.f, 0.f, 0.f, 0.f};
    #pragma unroll
    for (int i = 0; i < 4; ++i) {
        int row0i = quad * 4 + i, row1i = 16 + quad * 4 + i;
        int g0 = p0 + row0i; if (g0 >= end) g0 = end - 1;
        int g1 = p0 + row1i; if (g1 >= end) g1 = end - 1;
        int gr0 = brows[g0], gr1 = brows[g1];
        #pragma unroll
        for (int cb = 0; cb < 4; ++cb) {
            int col = c0 + cb * 16 + l16;
            float bias = eb2[e * H + col];
            float v0 = acc[0][cb][i] + bias;
            float v1 = acc[1][cb][i] + bias;
            vout[(size_t)gr0 * H + col] = v0;
            vout[(size_t)gr1 * H + col] = v1;
            rs0[i] += v0 * v0;
            rs1[i] += v1 * v1;
        }
    }
    #pragma unroll
    for (int i = 0; i < 4; ++i) {
        float s0 = rs0[i], s1 = rs1[i];
        #pragma unroll
        for (int off = 8; off; off >>= 1) {
            s0 += __shfl_xor(s0, off, 16);
            s1 += __shfl_xor(s1, off, 16);
        }
        if (l16 == 0) {
            int g0 = p0 + quad * 4 + i;      if (g0 >= end) g0 = end - 1;
            int g1 = p0 + 16 + quad * 4 + i; if (g1 >= end) g1 = end - 1;
            psum[(size_t)brows[g0] * 16 + cg] = s0;
            psum[(size_t)brows[g1] * 16 + cg] = s1;
        }
    }
}

// out = v * scale + q ; scale computed inline from psum (one block per row)
__global__ __launch_bounds__(256) void finalize_kernel(
    float* __restrict__ out, const float* __restrict__ q,
    const float* __restrict__ psum, const float* __restrict__ gval)
{
    const int row = blockIdx.x, t = threadIdx.x;
    float s = 0.f;
    #pragma unroll
    for (int j = 0; j < 16; ++j) s += psum[(size_t)row * 16 + j];
    float g = gval[row];
    float sc = g / fmaxf(g * sqrtf(s), 1e-6f);
    size_t i = (size_t)row * 256 + t;
    float4 v = ((const float4*)out)[i];
    float4 qq = ((const float4*)q)[i];
    float4 o;
    o.x = v.x * sc + qq.x;
    o.y = v.y * sc + qq.y;
    o.z = v.z * sc + qq.z;
    o.w = v.w * sc + qq.w;
    ((float4*)out)[i] = o;
}

extern "C" void kernel_launch(void* const* d_in, const int* in_sizes, int n_in,
                              void* d_out, int out_size, void* d_ws, size_t ws_size,
                              hipStream_t stream) {
    const float* q      = (const float*)d_in[0];
    const float* cls1_w = (const float*)d_in[1];
    const float* cls1_b = (const float*)d_in[2];
    const float* cls3_w = (const float*)d_in[3];
    const float* cls3_b = (const float*)d_in[4];
    const float* exp_w1 = (const float*)d_in[5];
    const float* exp_b1 = (const float*)d_in[6];
    const float* exp_w2 = (const float*)d_in[7];
    const float* exp_b2 = (const float*)d_in[8];
    float* out = (float*)d_out;

    // ---- workspace layout (~62 MB), lifetime-based aliasing ----
    char* w = (char*)d_ws;
    float* psum   = (float*)w;              w += (size_t)NB * 16 * 4;
    float* gvalp  = (float*)w;              w += (size_t)NB * 4;
    int* top1     = (int*)w;                w += (size_t)NB * 4;
    int* brows    = (int*)w;                w += (size_t)NB * 4;
    int* ambig_rows = (int*)w;              w += (size_t)NB * 4;
    int* counts   = (int*)w;                w += 16 * 4;
    int* offsets  = (int*)w;                w += 16 * 4;
    int* bpos     = (int*)w;                w += 16 * 4;
    int* ambig_cnt = (int*)w;               w += 4 * 4;
    int* tm_e     = (int*)w;                w += NTILES * 4;
    int* tm_p     = (int*)w;                w += NTILES * 4;
    int* tm_end   = (int*)w;                w += NTILES * 4;
    w = (char*)(((size_t)w + 15) & ~(size_t)15);
    unsigned short* qhi  = (unsigned short*)w;  w += (size_t)NB * H * 2;   // lives whole pipeline
    unsigned short* qlo  = (unsigned short*)w;  w += (size_t)NB * H * 2;   // dead after g1 -> ew2b
    unsigned short* x1hi = (unsigned short*)w;                              // dead after logits
    unsigned short* x1lo = x1hi + (size_t)NB * HH;  w += (size_t)NB * HH * 2 * 2;  // -> ew1b
    unsigned short* hbuf = (unsigned short*)w;  w += (size_t)NB * HH * 2;
    unsigned short* w1hi = (unsigned short*)w;  w += (size_t)HH * H * 2;
    unsigned short* w1lo = (unsigned short*)w;  w += (size_t)HH * H * 2;
    unsigned short* w3hi = (unsigned short*)w;  w += (size_t)NEXP * HH * 2;
    unsigned short* w3lo = (unsigned short*)w;  w += (size_t)NEXP * HH * 2;
    unsigned short* ew1b = x1hi;   // reused after logits
    unsigned short* ew2b = qlo;    // reused after g1

    cvtA_kernel<<<8712, 256, 0, stream>>>(q, cls1_w, cls3_w, qhi, qlo, w1hi, w1lo,
                                          w3hi, w3lo, counts, ambig_cnt);
    g1_kernel<<<dim3(NB / 128, 8), 256, 0, stream>>>(qhi, qlo, w1hi, w1lo, cls1_b, x1hi, x1lo);
    logits_kernel<<<NB / 32, 256, 0, stream>>>(x1hi, x1lo, w3hi, w3lo, cls3_b,
                                               top1, gvalp, counts, ambig_rows, ambig_cnt);
    fixup_kernel<<<256, 256, 0, stream>>>(q, cls1_w, cls1_b, cls3_w, cls3_b,
                                          ambig_rows, ambig_cnt, top1, gvalp, counts);
    cvtB_kernel<<<16384, 256, 0, stream>>>(exp_w1, exp_w2, ew1b, ew2b);
    offsets_kernel<<<1, 64, 0, stream>>>(counts, offsets, bpos, tm_e, tm_p, tm_end);
    scatter_kernel<<<NB / 256, 256, 0, stream>>>(top1, bpos, brows);
    exp1_kernel<<<dim3(NTILES, 8), 64, 0, stream>>>(qhi, ew1b, exp_b1,
                                                    tm_e, tm_p, tm_end, brows, hbuf);
    exp2_kernel<<<dim3(NTILES, 16), 64, 0, stream>>>(hbuf, ew2b, exp_b2,
                                                     tm_e, tm_p, tm_end, brows, out, psum);
    finalize_kernel<<<NB, 256, 0, stream>>>(out, q, psum, gvalp);
}

// Round 2
// 426.986 us; speedup vs baseline: 1.2108x; 1.1054x over previous
//
#include <hip/hip_runtime.h>
#include <math.h>

#define NB 8192
#define H 1024
#define HH 512
#define NEXP 16
#define NT128 96            // max sum of per-expert ceil(cnt/128) = 16 + 64, padded
#define AMBIG_THR 1e-3f     // ~50 sigma of split-bf16 logit error

// MFMA 16x16x32 bf16 fragments
typedef __attribute__((ext_vector_type(8))) short bfrag;
typedef __attribute__((ext_vector_type(4))) float f4;

__device__ __forceinline__ f4 MF(bfrag a, bfrag b, f4 c) {
    return __builtin_amdgcn_mfma_f32_16x16x32_bf16(a, b, c, 0, 0, 0);
}
__device__ __forceinline__ unsigned short f2bf(float f) {  // RNE fp32->bf16
    unsigned u = __float_as_uint(f);
    u += 0x7fff + ((u >> 16) & 1);
    return (unsigned short)(u >> 16);
}
__device__ __forceinline__ float bf2f(unsigned short h) {
    return __uint_as_float((unsigned)h << 16);
}

// async global->LDS, 16B per lane; LDS dest is wave-uniform base + lane*16
typedef __attribute__((address_space(1))) const unsigned GAS;
typedef __attribute__((address_space(3))) unsigned LAS;
__device__ __forceinline__ void gld16(const void* g, void* l) {
    __builtin_amdgcn_global_load_lds((GAS*)g, (LAS*)l, 16, 0, 0);
}

// fused split-conversion: q (8192 blocks), w1 (512), w3 (8); block 0 zeroes counters
__global__ __launch_bounds__(256) void cvtA_kernel(
    const float* __restrict__ q, const float* __restrict__ w1, const float* __restrict__ w3,
    unsigned short* __restrict__ qhi, unsigned short* __restrict__ qlo,
    unsigned short* __restrict__ w1hi, unsigned short* __restrict__ w1lo,
    unsigned short* __restrict__ w3hi, unsigned short* __restrict__ w3lo,
    int* __restrict__ counts, int* __restrict__ ambig_cnt)
{
    const int b = blockIdx.x, t = threadIdx.x;
    if (b == 0) {
        if (t < NEXP) counts[t] = 0;
        if (t == NEXP) ambig_cnt[0] = 0;
    }
    const float* src; unsigned short *hi, *lo; int i;
    if (b < 8192)      { src = q;  hi = qhi;  lo = qlo;  i = b * 256 + t; }
    else if (b < 8704) { src = w1; hi = w1hi; lo = w1lo; i = (b - 8192) * 256 + t; }
    else               { src = w3; hi = w3hi; lo = w3lo; i = (b - 8704) * 256 + t; }
    float4 v = ((const float4*)src)[i];
    ushort4 h, l;
    h.x = f2bf(v.x); l.x = f2bf(v.x - bf2f(h.x));
    h.y = f2bf(v.y); l.y = f2bf(v.y - bf2f(h.y));
    h.z = f2bf(v.z); l.z = f2bf(v.z - bf2f(h.z));
    h.w = f2bf(v.w); l.w = f2bf(v.w - bf2f(h.w));
    ((ushort4*)hi)[i] = h;
    ((ushort4*)lo)[i] = l;
}

// fused plain conversion: exp_w1 (8192 blocks), exp_w2 (8192 blocks)
__global__ __launch_bounds__(256) void cvtB_kernel(
    const float* __restrict__ ew1, const float* __restrict__ ew2,
    unsigned short* __restrict__ d1, unsigned short* __restrict__ d2)
{
    const int b = blockIdx.x, t = threadIdx.x;
    const float* src; unsigned short* dst; int i;
    if (b < 8192) { src = ew1; dst = d1; i = b * 256 + t; }
    else          { src = ew2; dst = d2; i = (b - 8192) * 256 + t; }
    float4 v = ((const float4*)src)[i];
    ushort4 h;
    h.x = f2bf(v.x); h.y = f2bf(v.y); h.z = f2bf(v.z); h.w = f2bf(v.w);
    ((ushort4*)dst)[i] = h;
}

// ---- gating GEMM1 (split 3-term): x1 = relu(q @ w1^T + b1), stored hi/lo ----
// LDS-staged: 128x64 tile, BK=32, 4 waves (each 32 rows x 64 cols), double-buffered
// global_load_lds(16B) staging. Swizzle (both sides): slot ^= (row&3)^((row>>2)&3)
// -> 2-way bank aliasing on ds_read_b128 (free). grid (64, 8), block 256.
__global__ __launch_bounds__(256) void g1_kernel(
    const unsigned short* __restrict__ qhi, const unsigned short* __restrict__ qlo,
    const unsigned short* __restrict__ w1hi, const unsigned short* __restrict__ w1lo,
    const float* __restrict__ b1,
    unsigned short* __restrict__ x1hi, unsigned short* __restrict__ x1lo)
{
    __shared__ unsigned short Ah[2][128][32];
    __shared__ unsigned short Al[2][128][32];
    __shared__ unsigned short Bh[2][64][32];
    __shared__ unsigned short Bl[2][64][32];

    const int t = threadIdx.x, w = t >> 6, lane = t & 63;
    const int quad = lane >> 4, l16 = lane & 15;
    const int rowA0 = blockIdx.x * 128;
    const int colB0 = blockIdx.y * 64;
    const int rl = lane >> 2, sl = lane & 3;   // staging: 16 rows x 4 slots per 1KB chunk

    const unsigned short* gsrc[6];
    unsigned short* lbase[6];
    int bstr[6];
    #pragma unroll
    for (int j = 0; j < 6; ++j) {
        int c = w + j * 4;
        int rloc; const unsigned short* s; unsigned short* d; int str;
        if (c < 8)       { rloc = c * 16 + rl;        s = qhi  + (size_t)(rowA0 + rloc) * H; d = &Ah[0][c * 16][0];        str = 128 * 32; }
        else if (c < 16) { rloc = (c - 8) * 16 + rl;  s = qlo  + (size_t)(rowA0 + rloc) * H; d = &Al[0][(c - 8) * 16][0];  str = 128 * 32; }
        else if (c < 20) { rloc = (c - 16) * 16 + rl; s = w1hi + (size_t)(colB0 + rloc) * H; d = &Bh[0][(c - 16) * 16][0]; str = 64 * 32; }
        else             { rloc = (c - 20) * 16 + rl; s = w1lo + (size_t)(colB0 + rloc) * H; d = &Bl[0][(c - 20) * 16][0]; str = 64 * 32; }
        int f = (rloc & 3) ^ ((rloc >> 2) & 3);
        gsrc[j]  = s + (sl ^ f) * 8;   // pre-swizzled k-slot in the source
        lbase[j] = d;
        bstr[j]  = str;
    }

    const f4 z4 = {0.f, 0.f, 0.f, 0.f};
    f4 acc[2][4] = {{z4, z4, z4, z4}, {z4, z4, z4, z4}};
    // read rows: A row = w*32 + l16 (+16), B row = cb*16 + l16 -> f = (l16&3)^(l16>>2)
    const int sw = (quad ^ (l16 & 3) ^ (l16 >> 2)) * 8;
    const int ra0 = w * 32 + l16, ra1 = ra0 + 16;

    auto STAGE = [&](int buf, int kt) {
        #pragma unroll
        for (int j = 0; j < 6; ++j)
            gld16(gsrc[j] + kt * 32, lbase[j] + buf * bstr[j]);
    };
    auto COMPUTE = [&](int buf) {
        bfrag ah0 = *(const bfrag*)&Ah[buf][ra0][sw];
        bfrag al0 = *(const bfrag*)&Al[buf][ra0][sw];
        bfrag ah1 = *(const bfrag*)&Ah[buf][ra1][sw];
        bfrag al1 = *(const bfrag*)&Al[buf][ra1][sw];
        #pragma unroll
        for (int cb = 0; cb < 4; ++cb) {
            bfrag bh = *(const bfrag*)&Bh[buf][cb * 16 + l16][sw];
            bfrag bl = *(const bfrag*)&Bl[buf][cb * 16 + l16][sw];
            acc[0][cb] = MF(al0, bh, MF(ah0, bl, MF(ah0, bh, acc[0][cb])));
            acc[1][cb] = MF(al1, bh, MF(ah1, bl, MF(ah1, bh, acc[1][cb])));
        }
    };

    STAGE(0, 0);
    __syncthreads();
    int cur = 0;
    for (int kt = 1; kt < 32; ++kt) {
        STAGE(cur ^ 1, kt);     // prefetch next K-tile while computing current
        COMPUTE(cur);
        __syncthreads();        // compiler drains vmcnt+lgkmcnt here (m97 structure)
        cur ^= 1;
    }
    COMPUTE(cur);

    const int row0 = rowA0 + w * 32;
    #pragma unroll
    for (int cb = 0; cb < 4; ++cb) {
        int col = colB0 + cb * 16 + l16;
        float bias = b1[col];
        #pragma unroll
        for (int rb = 0; rb < 2; ++rb)
            #pragma unroll
            for (int i = 0; i < 4; ++i) {
                int row = rb * 16 + quad * 4 + i;
                float v = fmaxf(acc[rb][cb][i] + bias, 0.f);
                unsigned short hh = f2bf(v);
                size_t idx = (size_t)(row0 + row) * HH + col;
                x1hi[idx] = hh;
                x1lo[idx] = f2bf(v - bf2f(hh));
            }
    }
}

// ---- logits (split 3-term) + argmax + gate + counts + ambiguity flag ----
__global__ __launch_bounds__(256) void logits_kernel(
    const unsigned short* __restrict__ x1hi, const unsigned short* __restrict__ x1lo,
    const unsigned short* __restrict__ w3hi, const unsigned short* __restrict__ w3lo,
    const float* __restrict__ b3,
    int* __restrict__ top1, float* __restrict__ gval, int* __restrict__ counts,
    int* __restrict__ ambig_rows, int* __restrict__ ambig_cnt)
{
    __shared__ float lgp[4][32][NEXP];
    const int t = threadIdx.x, wave = t >> 6, lane = t & 63;
    const int quad = lane >> 4, l16 = lane & 15;
    const int row0 = blockIdx.x * 32;
    const f4 z4 = {0.f, 0.f, 0.f, 0.f};

    f4 l0 = z4, l1 = z4;
    const size_t ar0 = (size_t)(row0 + l16) * HH + quad * 8;
    const size_t ar1 = ar0 + (size_t)16 * HH;
    const size_t br = (size_t)l16 * HH + quad * 8;
    #pragma unroll
    for (int ks = 0; ks < 4; ++ks) {
        int kk = wave * 128 + ks * 32;
        bfrag ah0 = *(const bfrag*)(x1hi + ar0 + kk);
        bfrag al0 = *(const bfrag*)(x1lo + ar0 + kk);
        bfrag ah1 = *(const bfrag*)(x1hi + ar1 + kk);
        bfrag al1 = *(const bfrag*)(x1lo + ar1 + kk);
        bfrag bh  = *(const bfrag*)(w3hi + br + kk);
        bfrag bl  = *(const bfrag*)(w3lo + br + kk);
        l0 = MF(al0, bh, MF(ah0, bl, MF(ah0, bh, l0)));
        l1 = MF(al1, bh, MF(ah1, bl, MF(ah1, bh, l1)));
    }
    #pragma unroll
    for (int i = 0; i < 4; ++i) {
        lgp[wave][quad * 4 + i][l16] = l0[i];
        lgp[wave][16 + quad * 4 + i][l16] = l1[i];
    }
    __syncthreads();

    if (t < 32) {
        float lg[NEXP];
        #pragma unroll
        for (int m = 0; m < NEXP; ++m)
            lg[m] = lgp[0][t][m] + lgp[1][t][m] + lgp[2][t][m] + lgp[3][t][m] + b3[m];
        float best = lg[0], second = -3.4e38f; int bi = 0;
        #pragma unroll
        for (int m = 1; m < NEXP; ++m) {
            float v = lg[m];
            if (v > best) { second = best; best = v; bi = m; }
            else if (v > second) second = v;
        }
        float se = 0.f;
        #pragma unroll
        for (int m = 0; m < NEXP; ++m) se += expf(lg[m] - best);
        int grow = row0 + t;
        top1[grow] = bi;
        gval[grow] = 1.f / se;
        atomicAdd(&counts[bi], 1);
        if (best - second < AMBIG_THR) {
            int pos = atomicAdd(ambig_cnt, 1);
            if (pos < NB) ambig_rows[pos] = grow;
        }
    }
}

// ---- exact fp32 recompute for ambiguous rows (expected ~2-5 rows) ----
__global__ __launch_bounds__(256) void fixup_kernel(
    const float* __restrict__ q, const float* __restrict__ w1, const float* __restrict__ b1,
    const float* __restrict__ w3, const float* __restrict__ b3,
    const int* __restrict__ ambig_rows, const int* __restrict__ ambig_cnt,
    int* __restrict__ top1, float* __restrict__ gval, int* __restrict__ counts)
{
    __shared__ __align__(16) float qrow[H];
    __shared__ __align__(16) float x1[HH];
    __shared__ float lgs[NEXP];
    const int t = threadIdx.x, wv = t >> 6, ln = t & 63;
    int nn = *ambig_cnt; if (nn > NB) nn = NB;
    for (int ii = blockIdx.x; ii < nn; ii += gridDim.x) {
        int row = ambig_rows[ii];
        ((float4*)qrow)[t] = ((const float4*)(q + (size_t)row * H))[t];
        __syncthreads();
        for (int c = wv * 2; c < HH; c += 8) {
            const float4* w0 = (const float4*)(w1 + (size_t)c * H);
            const float4* w1r = (const float4*)(w1 + (size_t)(c + 1) * H);
            const float4* qv = (const float4*)qrow;
            float s0 = 0.f, s1 = 0.f;
            #pragma unroll
            for (int j = 0; j < 4; ++j) {
                float4 a = qv[j * 64 + ln];
                float4 b0 = w0[j * 64 + ln];
                float4 b1v = w1r[j * 64 + ln];
                s0 += a.x * b0.x + a.y * b0.y + a.z * b0.z + a.w * b0.w;
                s1 += a.x * b1v.x + a.y * b1v.y + a.z * b1v.z + a.w * b1v.w;
            }
            #pragma unroll
            for (int off = 32; off; off >>= 1) {
                s0 += __shfl_xor(s0, off, 64);
                s1 += __shfl_xor(s1, off, 64);
            }
            if (ln == 0) {
                x1[c]     = fmaxf(s0 + b1[c], 0.f);
                x1[c + 1] = fmaxf(s1 + b1[c + 1], 0.f);
            }
        }
        __syncthreads();
        for (int m = wv; m < NEXP; m += 4) {
            const float4* wr = (const float4*)(w3 + (size_t)m * HH);
            const float4* xv = (const float4*)x1;
            float s = 0.f;
            #pragma unroll
            for (int j = 0; j < 2; ++j) {
                float4 a = xv[j * 64 + ln];
                float4 b = wr[j * 64 + ln];
                s += a.x * b.x + a.y * b.y + a.z * b.z + a.w * b.w;
            }
            #pragma unroll
            for (int off = 32; off; off >>= 1) s += __shfl_xor(s, off, 64);
            if (ln == 0) lgs[m] = s + b3[m];
        }
        __syncthreads();
        if (t == 0) {
            float best = lgs[0]; int bi = 0;
            #pragma unroll
            for (int m = 1; m < NEXP; ++m) if (lgs[m] > best) { best = lgs[m]; bi = m; }
            float se = 0.f;
            #pragma unroll
            for (int m = 0; m < NEXP; ++m) se += expf(lgs[m] - best);
            int old = top1[row];
            if (bi != old) {
                atomicSub(&counts[old], 1);
                atomicAdd(&counts[bi], 1);
                top1[row] = bi;
            }
            gval[row] = 1.f / se;
        }
        __syncthreads();
    }
}

// offsets + 128-row tile map
__global__ __launch_bounds__(64) void offsets_kernel(
    const int* __restrict__ counts, int* __restrict__ offsets, int* __restrict__ bpos,
    int* __restrict__ tm_e, int* __restrict__ tm_p, int* __restrict__ tm_end)
{
    if (threadIdx.x == 0) {
        int run = 0;
        for (int e = 0; e < NEXP; ++e) { offsets[e] = run; bpos[e] = run; run += counts[e]; }
        int tile = 0;
        for (int e = 0; e < NEXP; ++e) {
            int beg = offsets[e], end = beg + counts[e];
            for (int p = beg; p < end; p += 128) {
                tm_e[tile] = e; tm_p[tile] = p; tm_end[tile] = end; ++tile;
            }
        }
        for (; tile < NT128; ++tile) tm_e[tile] = -1;
    }
}

__global__ __launch_bounds__(256) void scatter_kernel(
    const int* __restrict__ top1, int* __restrict__ bpos, int* __restrict__ brows)
{
    int b = blockIdx.x * 256 + threadIdx.x;
    int e = top1[b];
    int pos = atomicAdd(&bpos[e], 1);
    brows[pos] = b;
}

// ---- expert GEMM1: h[pos][512] = relu(q[brows[pos]] @ w1[e]^T + b1[e]) ----
// LDS-staged: 128x64 tile, BK=32, 4 waves; A rows gathered via brows (per-lane
// global_load_lds sources). grid (NT128, 8), block 256.
__global__ __launch_bounds__(256) void exp1_kernel(
    const unsigned short* __restrict__ qb, const unsigned short* __restrict__ ew1b,
    const float* __restrict__ eb1,
    const int* __restrict__ tm_e, const int* __restrict__ tm_p, const int* __restrict__ tm_end,
    const int* __restrict__ brows, unsigned short* __restrict__ h)
{
    const int e = tm_e[blockIdx.x];
    if (e < 0) return;
    const int p0 = tm_p[blockIdx.x], end = tm_end[blockIdx.x];

    __shared__ unsigned short A[2][128][32];
    __shared__ unsigned short B[2][64][32];

    const int t = threadIdx.x, w = t >> 6, lane = t & 63;
    const int quad = lane >> 4, l16 = lane & 15;
    const int c0 = blockIdx.y * 64;
    const unsigned short* w1p = ew1b + (size_t)e * HH * H;
    const int rl = lane >> 2, sl = lane & 3;

    // 12 chunks: c 0-7 -> A rows c*16.., c 8-11 -> B rows (c-8)*16..
    const unsigned short* gsrc[3];
    unsigned short* lbase[3];
    int bstr[3];
    #pragma unroll
    for (int j = 0; j < 3; ++j) {
        int c = w + j * 4;
        int rloc; const unsigned short* s; unsigned short* d; int str;
        if (c < 8) {
            rloc = c * 16 + rl;
            int pa = p0 + rloc; if (pa >= end) pa = end - 1;   // ragged tail: duplicate last row
            s = qb + (size_t)brows[pa] * H;
            d = &A[0][c * 16][0]; str = 128 * 32;
        } else {
            rloc = (c - 8) * 16 + rl;
            s = w1p + (size_t)(c0 + rloc) * H;
            d = &B[0][(c - 8) * 16][0]; str = 64 * 32;
        }
        int f = (rloc & 3) ^ ((rloc >> 2) & 3);
        gsrc[j]  = s + (sl ^ f) * 8;
        lbase[j] = d;
        bstr[j]  = str;
    }

    const f4 z4 = {0.f, 0.f, 0.f, 0.f};
    f4 acc[2][4] = {{z4, z4, z4, z4}, {z4, z4, z4, z4}};
    const int sw = (quad ^ (l16 & 3) ^ (l16 >> 2)) * 8;
    const int ra0 = w * 32 + l16, ra1 = ra0 + 16;

    auto STAGE = [&](int buf, int kt) {
        #pragma unroll
        for (int j = 0; j < 3; ++j)
            gld16(gsrc[j] + kt * 32, lbase[j] + buf * bstr[j]);
    };
    auto COMPUTE = [&](int buf) {
        bfrag a0 = *(const bfrag*)&A[buf][ra0][sw];
        bfrag a1 = *(const bfrag*)&A[buf][ra1][sw];
        #pragma unroll
        for (int cb = 0; cb < 4; ++cb) {
            bfrag bb = *(const bfrag*)&B[buf][cb * 16 + l16][sw];
            acc[0][cb] = MF(a0, bb, acc[0][cb]);
            acc[1][cb] = MF(a1, bb, acc[1][cb]);
        }
    };

    STAGE(0, 0);
    __syncthreads();
    int cur = 0;
    for (int kt = 1; kt < 32; ++kt) {
        STAGE(cur ^ 1, kt);
        COMPUTE(cur);
        __syncthreads();
        cur ^= 1;
    }
    COMPUTE(cur);

    const int prow0 = p0 + w * 32;
    #pragma unroll
    for (int cb = 0; cb < 4; ++cb) {
        int col = c0 + cb * 16 + l16;
        float bias = eb1[e * HH + col];
        #pragma unroll
        for (int rb = 0; rb < 2; ++rb)
            #pragma unroll
            for (int i = 0; i < 4; ++i) {
                int row = rb * 16 + quad * 4 + i;
                if (prow0 + row < end)
                    h[(size_t)(prow0 + row) * HH + col] = f2bf(fmaxf(acc[rb][cb][i] + bias, 0.f));
            }
    }
}

// ---- expert GEMM2: v = h @ w2[e]^T + b2[e]; psum[row][cg] = partial sum v^2 ----
// LDS-staged: 128x64 tile, BK=32, 4 waves; A (h) is position-dense.
// grid (NT128, 16), block 256.
__global__ __launch_bounds__(256) void exp2_kernel(
    const unsigned short* __restrict__ h, const unsigned short* __restrict__ ew2b,
    const float* __restrict__ eb2,
    const int* __restrict__ tm_e, const int* __restrict__ tm_p, const int* __restrict__ tm_end,
    const int* __restrict__ brows,
    float* __restrict__ vout, float* __restrict__ psum)
{
    const int e = tm_e[blockIdx.x];
    if (e < 0) return;
    const int p0 = tm_p[blockIdx.x], end = tm_end[blockIdx.x];

    __shared__ unsigned short A[2][128][32];
    __shared__ unsigned short B[2][64][32];

    const int t = threadIdx.x, w = t >> 6, lane = t & 63;
    const int quad = lane >> 4, l16 = lane & 15;
    const int cg = blockIdx.y;
    const int c0 = cg * 64;
    const unsigned short* w2p = ew2b + (size_t)e * H * HH;
    const int rl = lane >> 2, sl = lane & 3;

    const unsigned short* gsrc[3];
    unsigned short* lbase[3];
    int bstr[3];
    #pragma unroll
    for (int j = 0; j < 3; ++j) {
        int c = w + j * 4;
        int rloc; const unsigned short* s; unsigned short* d; int str;
        if (c < 8) {
            rloc = c * 16 + rl;
            int pa = p0 + rloc; if (pa >= end) pa = end - 1;
            s = h + (size_t)pa * HH;
            d = &A[0][c * 16][0]; str = 128 * 32;
        } else {
            rloc = (c - 8) * 16 + rl;
            s = w2p + (size_t)(c0 + rloc) * HH;
            d = &B[0][(c - 8) * 16][0]; str = 64 * 32;
        }
        int f = (rloc & 3) ^ ((rloc >> 2) & 3);
        gsrc[j]  = s + (sl ^ f) * 8;
        lbase[j] = d;
        bstr[j]  = str;
    }

    const f4 z4 = {0.f, 0.f, 0.f, 0.f};
    f4 acc[2][4] = {{z4, z4, z4, z4}, {z4, z4, z4, z4}};
    const int sw = (quad ^ (l16 & 3) ^ (l16 >> 2)) * 8;
    const int ra0 = w * 32 + l16, ra1 = ra0 + 16;

    auto STAGE = [&](int buf, int kt) {
        #pragma unroll
        for (int j = 0; j < 3; ++j)
            gld16(gsrc[j] + kt * 32, lbase[j] + buf * bstr[j]);
    };
    auto COMPUTE = [&](int buf) {
        bfrag a0 = *(const bfrag*)&A[buf][ra0][sw];
        bfrag a1 = *(const bfrag*)&A[buf][ra1][sw];
        #pragma unroll
        for (int cb = 0; cb < 4; ++cb) {
            bfrag bb = *(const bfrag*)&B[buf][cb * 16 + l16][sw];
            acc[0][cb] = MF(a0, bb, acc[0][cb]);
            acc[1][cb] = MF(a1, bb, acc[1][cb]);
        }
    };

    STAGE(0, 0);
    __syncthreads();
    int cur = 0;
    for (int kt = 1; kt < 16; ++kt) {
        STAGE(cur ^ 1, kt);
        COMPUTE(cur);
        __syncthreads();
        cur ^= 1;
    }
    COMPUTE(cur);

    // bias + v-write + per-row sum(v^2); wave w owns positions p0+w*32 .. +31
    const int pw0 = p0 + w * 32;
    float rs0[4] = {0.f, 0.f, 0.f, 0.f}, rs1[4] = {0.f, 0.f, 0.f, 0.f};
    #pragma unroll
    for (int i = 0; i < 4; ++i) {
        int row0i = quad * 4 + i, row1i = 16 + quad * 4 + i;
        int g0 = pw0 + row0i; if (g0 >= end) g0 = end - 1;
        int g1 = pw0 + row1i; if (g1 >= end) g1 = end - 1;
        int gr0 = brows[g0], gr1 = brows[g1];
        #pragma unroll
        for (int cb = 0; cb < 4; ++cb) {
            int col = c0 + cb * 16 + l16;
            float bias = eb2[e * H + col];
            float v0 = acc[0][cb][i] + bias;
            float v1 = acc[1][cb][i] + bias;
            vout[(size_t)gr0 * H + col] = v0;
            vout[(size_t)gr1 * H + col] = v1;
            rs0[i] += v0 * v0;
            rs1[i] += v1 * v1;
        }
    }
    #pragma unroll
    for (int i = 0; i < 4; ++i) {
        float s0 = rs0[i], s1 = rs1[i];
        #pragma unroll
        for (int off = 8; off; off >>= 1) {
            s0 += __shfl_xor(s0, off, 16);
            s1 += __shfl_xor(s1, off, 16);
        }
        if (l16 == 0) {
            int g0 = pw0 + quad * 4 + i;      if (g0 >= end) g0 = end - 1;
            int g1 = pw0 + 16 + quad * 4 + i; if (g1 >= end) g1 = end - 1;
            psum[(size_t)brows[g0] * 16 + cg] = s0;
            psum[(size_t)brows[g1] * 16 + cg] = s1;
        }
    }
}

// out = v * scale + q ; scale computed inline from psum (one block per row)
__global__ __launch_bounds__(256) void finalize_kernel(
    float* __restrict__ out, const float* __restrict__ q,
    const float* __restrict__ psum, const float* __restrict__ gval)
{
    const int row = blockIdx.x, t = threadIdx.x;
    float s = 0.f;
    #pragma unroll
    for (int j = 0; j < 16; ++j) s += psum[(size_t)row * 16 + j];
    float g = gval[row];
    float sc = g / fmaxf(g * sqrtf(s), 1e-6f);
    size_t i = (size_t)row * 256 + t;
    float4 v = ((const float4*)out)[i];
    float4 qq = ((const float4*)q)[i];
    float4 o;
    o.x = v.x * sc + qq.x;
    o.y = v.y * sc + qq.y;
    o.z = v.z * sc + qq.z;
    o.w = v.w * sc + qq.w;
    ((float4*)out)[i] = o;
}

extern "C" void kernel_launch(void* const* d_in, const int* in_sizes, int n_in,
                              void* d_out, int out_size, void* d_ws, size_t ws_size,
                              hipStream_t stream) {
    const float* q      = (const float*)d_in[0];
    const float* cls1_w = (const float*)d_in[1];
    const float* cls1_b = (const float*)d_in[2];
    const float* cls3_w = (const float*)d_in[3];
    const float* cls3_b = (const float*)d_in[4];
    const float* exp_w1 = (const float*)d_in[5];
    const float* exp_b1 = (const float*)d_in[6];
    const float* exp_w2 = (const float*)d_in[7];
    const float* exp_b2 = (const float*)d_in[8];
    float* out = (float*)d_out;

    // ---- workspace layout (~62 MB), lifetime-based aliasing ----
    char* w = (char*)d_ws;
    float* psum   = (float*)w;              w += (size_t)NB * 16 * 4;
    float* gvalp  = (float*)w;              w += (size_t)NB * 4;
    int* top1     = (int*)w;                w += (size_t)NB * 4;
    int* brows    = (int*)w;                w += (size_t)NB * 4;
    int* ambig_rows = (int*)w;              w += (size_t)NB * 4;
    int* counts   = (int*)w;                w += 16 * 4;
    int* offsets  = (int*)w;                w += 16 * 4;
    int* bpos     = (int*)w;                w += 16 * 4;
    int* ambig_cnt = (int*)w;               w += 4 * 4;
    int* tm_e     = (int*)w;                w += NT128 * 4;
    int* tm_p     = (int*)w;                w += NT128 * 4;
    int* tm_end   = (int*)w;                w += NT128 * 4;
    w = (char*)(((size_t)w + 15) & ~(size_t)15);
    unsigned short* qhi  = (unsigned short*)w;  w += (size_t)NB * H * 2;   // lives whole pipeline
    unsigned short* qlo  = (unsigned short*)w;  w += (size_t)NB * H * 2;   // dead after g1 -> ew2b
    unsigned short* x1hi = (unsigned short*)w;                              // dead after logits
    unsigned short* x1lo = x1hi + (size_t)NB * HH;  w += (size_t)NB * HH * 2 * 2;  // -> ew1b
    unsigned short* hbuf = (unsigned short*)w;  w += (size_t)NB * HH * 2;
    unsigned short* w1hi = (unsigned short*)w;  w += (size_t)HH * H * 2;
    unsigned short* w1lo = (unsigned short*)w;  w += (size_t)HH * H * 2;
    unsigned short* w3hi = (unsigned short*)w;  w += (size_t)NEXP * HH * 2;
    unsigned short* w3lo = (unsigned short*)w;  w += (size_t)NEXP * HH * 2;
    unsigned short* ew1b = x1hi;   // reused after logits
    unsigned short* ew2b = qlo;    // reused after g1

    cvtA_kernel<<<8712, 256, 0, stream>>>(q, cls1_w, cls3_w, qhi, qlo, w1hi, w1lo,
                                          w3hi, w3lo, counts, ambig_cnt);
    g1_kernel<<<dim3(NB / 128, 8), 256, 0, stream>>>(qhi, qlo, w1hi, w1lo, cls1_b, x1hi, x1lo);
    logits_kernel<<<NB / 32, 256, 0, stream>>>(x1hi, x1lo, w3hi, w3lo, cls3_b,
                                               top1, gvalp, counts, ambig_rows, ambig_cnt);
    fixup_kernel<<<256, 256, 0, stream>>>(q, cls1_w, cls1_b, cls3_w, cls3_b,
                                          ambig_rows, ambig_cnt, top1, gvalp, counts);
    cvtB_kernel<<<16384, 256, 0, stream>>>(exp_w1, exp_w2, ew1b, ew2b);
    offsets_kernel<<<1, 64, 0, stream>>>(counts, offsets, bpos, tm_e, tm_p, tm_end);
    scatter_kernel<<<NB / 256, 256, 0, stream>>>(top1, bpos, brows);
    exp1_kernel<<<dim3(NT128, 8), 256, 0, stream>>>(qhi, ew1b, exp_b1,
                                                    tm_e, tm_p, tm_end, brows, hbuf);
    exp2_kernel<<<dim3(NT128, 16), 256, 0, stream>>>(hbuf, ew2b, exp_b2,
                                                     tm_e, tm_p, tm_end, brows, out, psum);
    finalize_kernel<<<NB, 256, 0, stream>>>(out, q, psum, gvalp);
}

// Round 3
// 381.745 us; speedup vs baseline: 1.3543x; 1.1185x over previous
//
#include <hip/hip_runtime.h>
#include <math.h>

#define NB 8192
#define H 1024
#define HH 512
#define NEXP 16
#define NT128 96            // max sum of per-expert ceil(cnt/128) = 16 + 64, padded
#define AMBIG_THR 1e-3f     // ~50 sigma of split-bf16 logit error

// MFMA 16x16x32 bf16 fragments
typedef __attribute__((ext_vector_type(8))) short bfrag;
typedef __attribute__((ext_vector_type(4))) float f4;

__device__ __forceinline__ f4 MF(bfrag a, bfrag b, f4 c) {
    return __builtin_amdgcn_mfma_f32_16x16x32_bf16(a, b, c, 0, 0, 0);
}
__device__ __forceinline__ unsigned short f2bf(float f) {  // RNE fp32->bf16
    unsigned u = __float_as_uint(f);
    u += 0x7fff + ((u >> 16) & 1);
    return (unsigned short)(u >> 16);
}
__device__ __forceinline__ float bf2f(unsigned short h) {
    return __uint_as_float((unsigned)h << 16);
}

// async global->LDS, 16B per lane; LDS dest is wave-uniform base + lane*16
typedef __attribute__((address_space(1))) const unsigned GAS;
typedef __attribute__((address_space(3))) unsigned LAS;
__device__ __forceinline__ void gld16(const void* g, void* l) {
    __builtin_amdgcn_global_load_lds((GAS*)g, (LAS*)l, 16, 0, 0);
}

// fused split-conversion: q (8192 blocks), w1 (512), w3 (8); block 0 zeroes counters
__global__ __launch_bounds__(256) void cvtA_kernel(
    const float* __restrict__ q, const float* __restrict__ w1, const float* __restrict__ w3,
    unsigned short* __restrict__ qhi, unsigned short* __restrict__ qlo,
    unsigned short* __restrict__ w1hi, unsigned short* __restrict__ w1lo,
    unsigned short* __restrict__ w3hi, unsigned short* __restrict__ w3lo,
    int* __restrict__ counts, int* __restrict__ ambig_cnt)
{
    const int b = blockIdx.x, t = threadIdx.x;
    if (b == 0) {
        if (t < NEXP) counts[t] = 0;
        if (t == NEXP) ambig_cnt[0] = 0;
    }
    const float* src; unsigned short *hi, *lo; int i;
    if (b < 8192)      { src = q;  hi = qhi;  lo = qlo;  i = b * 256 + t; }
    else if (b < 8704) { src = w1; hi = w1hi; lo = w1lo; i = (b - 8192) * 256 + t; }
    else               { src = w3; hi = w3hi; lo = w3lo; i = (b - 8704) * 256 + t; }
    float4 v = ((const float4*)src)[i];
    ushort4 h, l;
    h.x = f2bf(v.x); l.x = f2bf(v.x - bf2f(h.x));
    h.y = f2bf(v.y); l.y = f2bf(v.y - bf2f(h.y));
    h.z = f2bf(v.z); l.z = f2bf(v.z - bf2f(h.z));
    h.w = f2bf(v.w); l.w = f2bf(v.w - bf2f(h.w));
    ((ushort4*)hi)[i] = h;
    ((ushort4*)lo)[i] = l;
}

// fused plain conversion: exp_w1 (8192 blocks), exp_w2 (8192 blocks)
__global__ __launch_bounds__(256) void cvtB_kernel(
    const float* __restrict__ ew1, const float* __restrict__ ew2,
    unsigned short* __restrict__ d1, unsigned short* __restrict__ d2)
{
    const int b = blockIdx.x, t = threadIdx.x;
    const float* src; unsigned short* dst; int i;
    if (b < 8192) { src = ew1; dst = d1; i = b * 256 + t; }
    else          { src = ew2; dst = d2; i = (b - 8192) * 256 + t; }
    float4 v = ((const float4*)src)[i];
    ushort4 h;
    h.x = f2bf(v.x); h.y = f2bf(v.y); h.z = f2bf(v.z); h.w = f2bf(v.w);
    ((ushort4*)dst)[i] = h;
}

// ---- gating GEMM1 (split 3-term): x1 = relu(q @ w1^T + b1), stored hi/lo ----
// LDS-staged: 128x64 tile, BK=32, 4 waves (each 32 rows x 64 cols), double-buffered
// global_load_lds(16B) staging. Swizzle (both sides): slot ^= (row&3)^((row>>2)&3)
// -> 2-way bank aliasing on ds_read_b128 (free). grid (64, 8), block 256.
__global__ __launch_bounds__(256) void g1_kernel(
    const unsigned short* __restrict__ qhi, const unsigned short* __restrict__ qlo,
    const unsigned short* __restrict__ w1hi, const unsigned short* __restrict__ w1lo,
    const float* __restrict__ b1,
    unsigned short* __restrict__ x1hi, unsigned short* __restrict__ x1lo)
{
    __shared__ unsigned short Ah[2][128][32];
    __shared__ unsigned short Al[2][128][32];
    __shared__ unsigned short Bh[2][64][32];
    __shared__ unsigned short Bl[2][64][32];

    const int t = threadIdx.x, w = t >> 6, lane = t & 63;
    const int quad = lane >> 4, l16 = lane & 15;
    const int rowA0 = blockIdx.x * 128;
    const int colB0 = blockIdx.y * 64;
    const int rl = lane >> 2, sl = lane & 3;   // staging: 16 rows x 4 slots per 1KB chunk

    const unsigned short* gsrc[6];
    unsigned short* lbase[6];
    int bstr[6];
    #pragma unroll
    for (int j = 0; j < 6; ++j) {
        int c = w + j * 4;
        int rloc; const unsigned short* s; unsigned short* d; int str;
        if (c < 8)       { rloc = c * 16 + rl;        s = qhi  + (size_t)(rowA0 + rloc) * H; d = &Ah[0][c * 16][0];        str = 128 * 32; }
        else if (c < 16) { rloc = (c - 8) * 16 + rl;  s = qlo  + (size_t)(rowA0 + rloc) * H; d = &Al[0][(c - 8) * 16][0];  str = 128 * 32; }
        else if (c < 20) { rloc = (c - 16) * 16 + rl; s = w1hi + (size_t)(colB0 + rloc) * H; d = &Bh[0][(c - 16) * 16][0]; str = 64 * 32; }
        else             { rloc = (c - 20) * 16 + rl; s = w1lo + (size_t)(colB0 + rloc) * H; d = &Bl[0][(c - 20) * 16][0]; str = 64 * 32; }
        int f = (rloc & 3) ^ ((rloc >> 2) & 3);
        gsrc[j]  = s + (sl ^ f) * 8;   // pre-swizzled k-slot in the source
        lbase[j] = d;
        bstr[j]  = str;
    }

    const f4 z4 = {0.f, 0.f, 0.f, 0.f};
    f4 acc[2][4] = {{z4, z4, z4, z4}, {z4, z4, z4, z4}};
    const int sw = (quad ^ (l16 & 3) ^ (l16 >> 2)) * 8;
    const int ra0 = w * 32 + l16, ra1 = ra0 + 16;

    auto STAGE = [&](int buf, int kt) {
        #pragma unroll
        for (int j = 0; j < 6; ++j)
            gld16(gsrc[j] + kt * 32, lbase[j] + buf * bstr[j]);
    };
    auto COMPUTE = [&](int buf) {
        bfrag ah0 = *(const bfrag*)&Ah[buf][ra0][sw];
        bfrag al0 = *(const bfrag*)&Al[buf][ra0][sw];
        bfrag ah1 = *(const bfrag*)&Ah[buf][ra1][sw];
        bfrag al1 = *(const bfrag*)&Al[buf][ra1][sw];
        #pragma unroll
        for (int cb = 0; cb < 4; ++cb) {
            bfrag bh = *(const bfrag*)&Bh[buf][cb * 16 + l16][sw];
            bfrag bl = *(const bfrag*)&Bl[buf][cb * 16 + l16][sw];
            acc[0][cb] = MF(al0, bh, MF(ah0, bl, MF(ah0, bh, acc[0][cb])));
            acc[1][cb] = MF(al1, bh, MF(ah1, bl, MF(ah1, bh, acc[1][cb])));
        }
    };

    STAGE(0, 0);
    __syncthreads();
    int cur = 0;
    for (int kt = 1; kt < 32; ++kt) {
        STAGE(cur ^ 1, kt);     // prefetch next K-tile while computing current
        COMPUTE(cur);
        __syncthreads();        // compiler drains vmcnt+lgkmcnt here (m97 structure)
        cur ^= 1;
    }
    COMPUTE(cur);

    const int row0 = rowA0 + w * 32;
    #pragma unroll
    for (int cb = 0; cb < 4; ++cb) {
        int col = colB0 + cb * 16 + l16;
        float bias = b1[col];
        #pragma unroll
        for (int rb = 0; rb < 2; ++rb)
            #pragma unroll
            for (int i = 0; i < 4; ++i) {
                int row = rb * 16 + quad * 4 + i;
                float v = fmaxf(acc[rb][cb][i] + bias, 0.f);
                unsigned short hh = f2bf(v);
                size_t idx = (size_t)(row0 + row) * HH + col;
                x1hi[idx] = hh;
                x1lo[idx] = f2bf(v - bf2f(hh));
            }
    }
}

// ---- logits (split 3-term) + argmax + gate + counts + ambiguity flag ----
__global__ __launch_bounds__(256) void logits_kernel(
    const unsigned short* __restrict__ x1hi, const unsigned short* __restrict__ x1lo,
    const unsigned short* __restrict__ w3hi, const unsigned short* __restrict__ w3lo,
    const float* __restrict__ b3,
    int* __restrict__ top1, float* __restrict__ gval, int* __restrict__ counts,
    int* __restrict__ ambig_rows, int* __restrict__ ambig_cnt)
{
    __shared__ float lgp[4][32][NEXP];
    const int t = threadIdx.x, wave = t >> 6, lane = t & 63;
    const int quad = lane >> 4, l16 = lane & 15;
    const int row0 = blockIdx.x * 32;
    const f4 z4 = {0.f, 0.f, 0.f, 0.f};

    f4 l0 = z4, l1 = z4;
    const size_t ar0 = (size_t)(row0 + l16) * HH + quad * 8;
    const size_t ar1 = ar0 + (size_t)16 * HH;
    const size_t br = (size_t)l16 * HH + quad * 8;
    #pragma unroll
    for (int ks = 0; ks < 4; ++ks) {
        int kk = wave * 128 + ks * 32;
        bfrag ah0 = *(const bfrag*)(x1hi + ar0 + kk);
        bfrag al0 = *(const bfrag*)(x1lo + ar0 + kk);
        bfrag ah1 = *(const bfrag*)(x1hi + ar1 + kk);
        bfrag al1 = *(const bfrag*)(x1lo + ar1 + kk);
        bfrag bh  = *(const bfrag*)(w3hi + br + kk);
        bfrag bl  = *(const bfrag*)(w3lo + br + kk);
        l0 = MF(al0, bh, MF(ah0, bl, MF(ah0, bh, l0)));
        l1 = MF(al1, bh, MF(ah1, bl, MF(ah1, bh, l1)));
    }
    #pragma unroll
    for (int i = 0; i < 4; ++i) {
        lgp[wave][quad * 4 + i][l16] = l0[i];
        lgp[wave][16 + quad * 4 + i][l16] = l1[i];
    }
    __syncthreads();

    if (t < 32) {
        float lg[NEXP];
        #pragma unroll
        for (int m = 0; m < NEXP; ++m)
            lg[m] = lgp[0][t][m] + lgp[1][t][m] + lgp[2][t][m] + lgp[3][t][m] + b3[m];
        float best = lg[0], second = -3.4e38f; int bi = 0;
        #pragma unroll
        for (int m = 1; m < NEXP; ++m) {
            float v = lg[m];
            if (v > best) { second = best; best = v; bi = m; }
            else if (v > second) second = v;
        }
        float se = 0.f;
        #pragma unroll
        for (int m = 0; m < NEXP; ++m) se += expf(lg[m] - best);
        int grow = row0 + t;
        top1[grow] = bi;
        gval[grow] = 1.f / se;
        atomicAdd(&counts[bi], 1);
        if (best - second < AMBIG_THR) {
            int pos = atomicAdd(ambig_cnt, 1);
            if (pos < NB) ambig_rows[pos] = grow;
        }
    }
}

// ---- exact fp32 x1 recompute for ambiguous rows, column-parallel ----
// grid 256 = 32 row-slots x 8 column-chunks (64 cols each); x1buf is fp32 [nn][HH].
__global__ __launch_bounds__(256) void fixup1_kernel(
    const float* __restrict__ q, const float* __restrict__ w1, const float* __restrict__ b1,
    const int* __restrict__ ambig_rows, const int* __restrict__ ambig_cnt,
    float* __restrict__ x1buf)
{
    __shared__ __align__(16) float qrow[H];
    const int t = threadIdx.x, wv = t >> 6, ln = t & 63;
    const int chunk = blockIdx.x & 7;        // 8 chunks of 64 columns
    const int slot  = blockIdx.x >> 3;       // 32 row slots
    const int base  = chunk * 64;
    int nn = *ambig_cnt; if (nn > NB) nn = NB;
    for (int ii = slot; ii < nn; ii += 32) {
        int row = ambig_rows[ii];
        ((float4*)qrow)[t] = ((const float4*)(q + (size_t)row * H))[t];
        __syncthreads();
        for (int c = base + wv * 2; c < base + 64; c += 8) {
            const float4* w0 = (const float4*)(w1 + (size_t)c * H);
            const float4* w1r = (const float4*)(w1 + (size_t)(c + 1) * H);
            const float4* qv = (const float4*)qrow;
            float s0 = 0.f, s1 = 0.f;
            #pragma unroll
            for (int j = 0; j < 4; ++j) {
                float4 a = qv[j * 64 + ln];
                float4 b0 = w0[j * 64 + ln];
                float4 b1v = w1r[j * 64 + ln];
                s0 += a.x * b0.x + a.y * b0.y + a.z * b0.z + a.w * b0.w;
                s1 += a.x * b1v.x + a.y * b1v.y + a.z * b1v.z + a.w * b1v.w;
            }
            #pragma unroll
            for (int off = 32; off; off >>= 1) {
                s0 += __shfl_xor(s0, off, 64);
                s1 += __shfl_xor(s1, off, 64);
            }
            if (ln == 0) {
                x1buf[(size_t)ii * HH + c]     = fmaxf(s0 + b1[c], 0.f);
                x1buf[(size_t)ii * HH + c + 1] = fmaxf(s1 + b1[c + 1], 0.f);
            }
        }
        __syncthreads();
    }
}

// ---- logits from exact x1 + top1/gval/counts update (one block per ambig row) ----
__global__ __launch_bounds__(256) void fixup2_kernel(
    const float* __restrict__ x1buf,
    const float* __restrict__ w3, const float* __restrict__ b3,
    const int* __restrict__ ambig_rows, const int* __restrict__ ambig_cnt,
    int* __restrict__ top1, float* __restrict__ gval, int* __restrict__ counts)
{
    __shared__ float lgs[NEXP];
    const int t = threadIdx.x, wv = t >> 6, ln = t & 63;
    int nn = *ambig_cnt; if (nn > NB) nn = NB;
    for (int ii = blockIdx.x; ii < nn; ii += gridDim.x) {
        int row = ambig_rows[ii];
        const float4* xv = (const float4*)(x1buf + (size_t)ii * HH);
        for (int m = wv; m < NEXP; m += 4) {
            const float4* wr = (const float4*)(w3 + (size_t)m * HH);
            float s = 0.f;
            #pragma unroll
            for (int j = 0; j < 2; ++j) {
                float4 a = xv[j * 64 + ln];
                float4 b = wr[j * 64 + ln];
                s += a.x * b.x + a.y * b.y + a.z * b.z + a.w * b.w;
            }
            #pragma unroll
            for (int off = 32; off; off >>= 1) s += __shfl_xor(s, off, 64);
            if (ln == 0) lgs[m] = s + b3[m];
        }
        __syncthreads();
        if (t == 0) {
            float best = lgs[0]; int bi = 0;
            #pragma unroll
            for (int m = 1; m < NEXP; ++m) if (lgs[m] > best) { best = lgs[m]; bi = m; }
            float se = 0.f;
            #pragma unroll
            for (int m = 0; m < NEXP; ++m) se += expf(lgs[m] - best);
            int old = top1[row];
            if (bi != old) {
                atomicSub(&counts[old], 1);
                atomicAdd(&counts[bi], 1);
                top1[row] = bi;
            }
            gval[row] = 1.f / se;
        }
        __syncthreads();
    }
}

// offsets + 128-row tile map
__global__ __launch_bounds__(64) void offsets_kernel(
    const int* __restrict__ counts, int* __restrict__ offsets, int* __restrict__ bpos,
    int* __restrict__ tm_e, int* __restrict__ tm_p, int* __restrict__ tm_end)
{
    if (threadIdx.x == 0) {
        int run = 0;
        for (int e = 0; e < NEXP; ++e) { offsets[e] = run; bpos[e] = run; run += counts[e]; }
        int tile = 0;
        for (int e = 0; e < NEXP; ++e) {
            int beg = offsets[e], end = beg + counts[e];
            for (int p = beg; p < end; p += 128) {
                tm_e[tile] = e; tm_p[tile] = p; tm_end[tile] = end; ++tile;
            }
        }
        for (; tile < NT128; ++tile) tm_e[tile] = -1;
    }
}

__global__ __launch_bounds__(256) void scatter_kernel(
    const int* __restrict__ top1, int* __restrict__ bpos, int* __restrict__ brows)
{
    int b = blockIdx.x * 256 + threadIdx.x;
    int e = top1[b];
    int pos = atomicAdd(&bpos[e], 1);
    brows[pos] = b;
}

// ---- expert GEMM1: h[pos][512] = relu(q[brows[pos]] @ w1[e]^T + b1[e]) ----
// LDS-staged: 128x64 tile, BK=32, 4 waves; A rows gathered via brows (per-lane
// global_load_lds sources). grid (NT128, 8), block 256.
__global__ __launch_bounds__(256) void exp1_kernel(
    const unsigned short* __restrict__ qb, const unsigned short* __restrict__ ew1b,
    const float* __restrict__ eb1,
    const int* __restrict__ tm_e, const int* __restrict__ tm_p, const int* __restrict__ tm_end,
    const int* __restrict__ brows, unsigned short* __restrict__ h)
{
    const int e = tm_e[blockIdx.x];
    if (e < 0) return;
    const int p0 = tm_p[blockIdx.x], end = tm_end[blockIdx.x];

    __shared__ unsigned short A[2][128][32];
    __shared__ unsigned short B[2][64][32];

    const int t = threadIdx.x, w = t >> 6, lane = t & 63;
    const int quad = lane >> 4, l16 = lane & 15;
    const int c0 = blockIdx.y * 64;
    const unsigned short* w1p = ew1b + (size_t)e * HH * H;
    const int rl = lane >> 2, sl = lane & 3;

    const unsigned short* gsrc[3];
    unsigned short* lbase[3];
    int bstr[3];
    #pragma unroll
    for (int j = 0; j < 3; ++j) {
        int c = w + j * 4;
        int rloc; const unsigned short* s; unsigned short* d; int str;
        if (c < 8) {
            rloc = c * 16 + rl;
            int pa = p0 + rloc; if (pa >= end) pa = end - 1;   // ragged tail: duplicate last row
            s = qb + (size_t)brows[pa] * H;
            d = &A[0][c * 16][0]; str = 128 * 32;
        } else {
            rloc = (c - 8) * 16 + rl;
            s = w1p + (size_t)(c0 + rloc) * H;
            d = &B[0][(c - 8) * 16][0]; str = 64 * 32;
        }
        int f = (rloc & 3) ^ ((rloc >> 2) & 3);
        gsrc[j]  = s + (sl ^ f) * 8;
        lbase[j] = d;
        bstr[j]  = str;
    }

    const f4 z4 = {0.f, 0.f, 0.f, 0.f};
    f4 acc[2][4] = {{z4, z4, z4, z4}, {z4, z4, z4, z4}};
    const int sw = (quad ^ (l16 & 3) ^ (l16 >> 2)) * 8;
    const int ra0 = w * 32 + l16, ra1 = ra0 + 16;

    auto STAGE = [&](int buf, int kt) {
        #pragma unroll
        for (int j = 0; j < 3; ++j)
            gld16(gsrc[j] + kt * 32, lbase[j] + buf * bstr[j]);
    };
    auto COMPUTE = [&](int buf) {
        bfrag a0 = *(const bfrag*)&A[buf][ra0][sw];
        bfrag a1 = *(const bfrag*)&A[buf][ra1][sw];
        #pragma unroll
        for (int cb = 0; cb < 4; ++cb) {
            bfrag bb = *(const bfrag*)&B[buf][cb * 16 + l16][sw];
            acc[0][cb] = MF(a0, bb, acc[0][cb]);
            acc[1][cb] = MF(a1, bb, acc[1][cb]);
        }
    };

    STAGE(0, 0);
    __syncthreads();
    int cur = 0;
    for (int kt = 1; kt < 32; ++kt) {
        STAGE(cur ^ 1, kt);
        COMPUTE(cur);
        __syncthreads();
        cur ^= 1;
    }
    COMPUTE(cur);

    const int prow0 = p0 + w * 32;
    #pragma unroll
    for (int cb = 0; cb < 4; ++cb) {
        int col = c0 + cb * 16 + l16;
        float bias = eb1[e * HH + col];
        #pragma unroll
        for (int rb = 0; rb < 2; ++rb)
            #pragma unroll
            for (int i = 0; i < 4; ++i) {
                int row = rb * 16 + quad * 4 + i;
                if (prow0 + row < end)
                    h[(size_t)(prow0 + row) * HH + col] = f2bf(fmaxf(acc[rb][cb][i] + bias, 0.f));
            }
    }
}

// ---- expert GEMM2: v = h @ w2[e]^T + b2[e]; psum[row][cg] = partial sum v^2 ----
// LDS-staged: 128x64 tile, BK=32, 4 waves; A (h) is position-dense.
// grid (NT128, 16), block 256.
__global__ __launch_bounds__(256) void exp2_kernel(
    const unsigned short* __restrict__ h, const unsigned short* __restrict__ ew2b,
    const float* __restrict__ eb2,
    const int* __restrict__ tm_e, const int* __restrict__ tm_p, const int* __restrict__ tm_end,
    const int* __restrict__ brows,
    float* __restrict__ vout, float* __restrict__ psum)
{
    const int e = tm_e[blockIdx.x];
    if (e < 0) return;
    const int p0 = tm_p[blockIdx.x], end = tm_end[blockIdx.x];

    __shared__ unsigned short A[2][128][32];
    __shared__ unsigned short B[2][64][32];

    const int t = threadIdx.x, w = t >> 6, lane = t & 63;
    const int quad = lane >> 4, l16 = lane & 15;
    const int cg = blockIdx.y;
    const int c0 = cg * 64;
    const unsigned short* w2p = ew2b + (size_t)e * H * HH;
    const int rl = lane >> 2, sl = lane & 3;

    const unsigned short* gsrc[3];
    unsigned short* lbase[3];
    int bstr[3];
    #pragma unroll
    for (int j = 0; j < 3; ++j) {
        int c = w + j * 4;
        int rloc; const unsigned short* s; unsigned short* d; int str;
        if (c < 8) {
            rloc = c * 16 + rl;
            int pa = p0 + rloc; if (pa >= end) pa = end - 1;
            s = h + (size_t)pa * HH;
            d = &A[0][c * 16][0]; str = 128 * 32;
        } else {
            rloc = (c - 8) * 16 + rl;
            s = w2p + (size_t)(c0 + rloc) * HH;
            d = &B[0][(c - 8) * 16][0]; str = 64 * 32;
        }
        int f = (rloc & 3) ^ ((rloc >> 2) & 3);
        gsrc[j]  = s + (sl ^ f) * 8;
        lbase[j] = d;
        bstr[j]  = str;
    }

    const f4 z4 = {0.f, 0.f, 0.f, 0.f};
    f4 acc[2][4] = {{z4, z4, z4, z4}, {z4, z4, z4, z4}};
    const int sw = (quad ^ (l16 & 3) ^ (l16 >> 2)) * 8;
    const int ra0 = w * 32 + l16, ra1 = ra0 + 16;

    auto STAGE = [&](int buf, int kt) {
        #pragma unroll
        for (int j = 0; j < 3; ++j)
            gld16(gsrc[j] + kt * 32, lbase[j] + buf * bstr[j]);
    };
    auto COMPUTE = [&](int buf) {
        bfrag a0 = *(const bfrag*)&A[buf][ra0][sw];
        bfrag a1 = *(const bfrag*)&A[buf][ra1][sw];
        #pragma unroll
        for (int cb = 0; cb < 4; ++cb) {
            bfrag bb = *(const bfrag*)&B[buf][cb * 16 + l16][sw];
            acc[0][cb] = MF(a0, bb, acc[0][cb]);
            acc[1][cb] = MF(a1, bb, acc[1][cb]);
        }
    };

    STAGE(0, 0);
    __syncthreads();
    int cur = 0;
    for (int kt = 1; kt < 16; ++kt) {
        STAGE(cur ^ 1, kt);
        COMPUTE(cur);
        __syncthreads();
        cur ^= 1;
    }
    COMPUTE(cur);

    // bias + v-write + per-row sum(v^2); wave w owns positions p0+w*32 .. +31
    const int pw0 = p0 + w * 32;
    float rs0[4] = {0.f, 0.f, 0.f, 0.f}, rs1[4] = {0.f, 0.f, 0.f, 0.f};
    #pragma unroll
    for (int i = 0; i < 4; ++i) {
        int row0i = quad * 4 + i, row1i = 16 + quad * 4 + i;
        int g0 = pw0 + row0i; if (g0 >= end) g0 = end - 1;
        int g1 = pw0 + row1i; if (g1 >= end) g1 = end - 1;
        int gr0 = brows[g0], gr1 = brows[g1];
        #pragma unroll
        for (int cb = 0; cb < 4; ++cb) {
            int col = c0 + cb * 16 + l16;
            float bias = eb2[e * H + col];
            float v0 = acc[0][cb][i] + bias;
            float v1 = acc[1][cb][i] + bias;
            vout[(size_t)gr0 * H + col] = v0;
            vout[(size_t)gr1 * H + col] = v1;
            rs0[i] += v0 * v0;
            rs1[i] += v1 * v1;
        }
    }
    #pragma unroll
    for (int i = 0; i < 4; ++i) {
        float s0 = rs0[i], s1 = rs1[i];
        #pragma unroll
        for (int off = 8; off; off >>= 1) {
            s0 += __shfl_xor(s0, off, 16);
            s1 += __shfl_xor(s1, off, 16);
        }
        if (l16 == 0) {
            int g0 = pw0 + quad * 4 + i;      if (g0 >= end) g0 = end - 1;
            int g1 = pw0 + 16 + quad * 4 + i; if (g1 >= end) g1 = end - 1;
            psum[(size_t)brows[g0] * 16 + cg] = s0;
            psum[(size_t)brows[g1] * 16 + cg] = s1;
        }
    }
}

// out = v * scale + q ; scale computed inline from psum (one block per row)
__global__ __launch_bounds__(256) void finalize_kernel(
    float* __restrict__ out, const float* __restrict__ q,
    const float* __restrict__ psum, const float* __restrict__ gval)
{
    const int row = blockIdx.x, t = threadIdx.x;
    float s = 0.f;
    #pragma unroll
    for (int j = 0; j < 16; ++j) s += psum[(size_t)row * 16 + j];
    float g = gval[row];
    float sc = g / fmaxf(g * sqrtf(s), 1e-6f);
    size_t i = (size_t)row * 256 + t;
    float4 v = ((const float4*)out)[i];
    float4 qq = ((const float4*)q)[i];
    float4 o;
    o.x = v.x * sc + qq.x;
    o.y = v.y * sc + qq.y;
    o.z = v.z * sc + qq.z;
    o.w = v.w * sc + qq.w;
    ((float4*)out)[i] = o;
}

extern "C" void kernel_launch(void* const* d_in, const int* in_sizes, int n_in,
                              void* d_out, int out_size, void* d_ws, size_t ws_size,
                              hipStream_t stream) {
    const float* q      = (const float*)d_in[0];
    const float* cls1_w = (const float*)d_in[1];
    const float* cls1_b = (const float*)d_in[2];
    const float* cls3_w = (const float*)d_in[3];
    const float* cls3_b = (const float*)d_in[4];
    const float* exp_w1 = (const float*)d_in[5];
    const float* exp_b1 = (const float*)d_in[6];
    const float* exp_w2 = (const float*)d_in[7];
    const float* exp_b2 = (const float*)d_in[8];
    float* out = (float*)d_out;

    // ---- workspace layout (~62 MB), lifetime-based aliasing ----
    char* w = (char*)d_ws;
    float* psum   = (float*)w;              w += (size_t)NB * 16 * 4;
    float* gvalp  = (float*)w;              w += (size_t)NB * 4;
    int* top1     = (int*)w;                w += (size_t)NB * 4;
    int* brows    = (int*)w;                w += (size_t)NB * 4;
    int* ambig_rows = (int*)w;              w += (size_t)NB * 4;
    int* counts   = (int*)w;                w += 16 * 4;
    int* offsets  = (int*)w;                w += 16 * 4;
    int* bpos     = (int*)w;                w += 16 * 4;
    int* ambig_cnt = (int*)w;               w += 4 * 4;
    int* tm_e     = (int*)w;                w += NT128 * 4;
    int* tm_p     = (int*)w;                w += NT128 * 4;
    int* tm_end   = (int*)w;                w += NT128 * 4;
    w = (char*)(((size_t)w + 15) & ~(size_t)15);
    unsigned short* qhi  = (unsigned short*)w;  w += (size_t)NB * H * 2;   // lives whole pipeline
    unsigned short* qlo  = (unsigned short*)w;  w += (size_t)NB * H * 2;   // dead after g1 -> ew2b
    unsigned short* x1hi = (unsigned short*)w;                              // dead after logits
    unsigned short* x1lo = x1hi + (size_t)NB * HH;  w += (size_t)NB * HH * 2 * 2;  // -> x1buf -> ew1b
    unsigned short* hbuf = (unsigned short*)w;  w += (size_t)NB * HH * 2;
    unsigned short* w1hi = (unsigned short*)w;  w += (size_t)HH * H * 2;
    unsigned short* w1lo = (unsigned short*)w;  w += (size_t)HH * H * 2;
    unsigned short* w3hi = (unsigned short*)w;  w += (size_t)NEXP * HH * 2;
    unsigned short* w3lo = (unsigned short*)w;  w += (size_t)NEXP * HH * 2;
    unsigned short* ew1b = x1hi;   // reused after logits+fixup
    unsigned short* ew2b = qlo;    // reused after g1
    float* x1buf = (float*)x1hi;   // fp32 [NB][HH] alias: dead x1hi/x1lo = 16 MB, used fixup1->fixup2

    cvtA_kernel<<<8712, 256, 0, stream>>>(q, cls1_w, cls3_w, qhi, qlo, w1hi, w1lo,
                                          w3hi, w3lo, counts, ambig_cnt);
    g1_kernel<<<dim3(NB / 128, 8), 256, 0, stream>>>(qhi, qlo, w1hi, w1lo, cls1_b, x1hi, x1lo);
    logits_kernel<<<NB / 32, 256, 0, stream>>>(x1hi, x1lo, w3hi, w3lo, cls3_b,
                                               top1, gvalp, counts, ambig_rows, ambig_cnt);
    fixup1_kernel<<<256, 256, 0, stream>>>(q, cls1_w, cls1_b, ambig_rows, ambig_cnt, x1buf);
    fixup2_kernel<<<64, 256, 0, stream>>>(x1buf, cls3_w, cls3_b, ambig_rows, ambig_cnt,
                                          top1, gvalp, counts);
    cvtB_kernel<<<16384, 256, 0, stream>>>(exp_w1, exp_w2, ew1b, ew2b);
    offsets_kernel<<<1, 64, 0, stream>>>(counts, offsets, bpos, tm_e, tm_p, tm_end);
    scatter_kernel<<<NB / 256, 256, 0, stream>>>(top1, bpos, brows);
    exp1_kernel<<<dim3(NT128, 8), 256, 0, stream>>>(qhi, ew1b, exp_b1,
                                                    tm_e, tm_p, tm_end, brows, hbuf);
    exp2_kernel<<<dim3(NT128, 16), 256, 0, stream>>>(hbuf, ew2b, exp_b2,
                                                     tm_e, tm_p, tm_end, brows, out, psum);
    finalize_kernel<<<NB, 256, 0, stream>>>(out, q, psum, gvalp);
}

// Round 4
// 356.603 us; speedup vs baseline: 1.4498x; 1.0705x over previous
//
#include <hip/hip_runtime.h>
#include <math.h>

#define NB 8192
#define H 1024
#define HH 512
#define NEXP 16
#define NT128 96            // max sum of per-expert ceil(cnt/128) = 16 + 64, padded
#define AMBIG_THR 1e-3f     // ~50 sigma of split-bf16 logit error

// MFMA 16x16x32 bf16 fragments
typedef __attribute__((ext_vector_type(8))) short bfrag;
typedef __attribute__((ext_vector_type(4))) float f4;

__device__ __forceinline__ f4 MF(bfrag a, bfrag b, f4 c) {
    return __builtin_amdgcn_mfma_f32_16x16x32_bf16(a, b, c, 0, 0, 0);
}
__device__ __forceinline__ unsigned short f2bf(float f) {  // RNE fp32->bf16
    unsigned u = __float_as_uint(f);
    u += 0x7fff + ((u >> 16) & 1);
    return (unsigned short)(u >> 16);
}
__device__ __forceinline__ float bf2f(unsigned short h) {
    return __uint_as_float((unsigned)h << 16);
}

// async global->LDS, 16B per lane; LDS dest is wave-uniform base + lane*16
typedef __attribute__((address_space(1))) const unsigned GAS;
typedef __attribute__((address_space(3))) unsigned LAS;
__device__ __forceinline__ void gld16(const void* g, void* l) {
    __builtin_amdgcn_global_load_lds((GAS*)g, (LAS*)l, 16, 0, 0);
}

// fused split-conversion: q (8192 blocks), w1 (512), w3 (8); block 0 zeroes counters
__global__ __launch_bounds__(256) void cvtA_kernel(
    const float* __restrict__ q, const float* __restrict__ w1, const float* __restrict__ w3,
    unsigned short* __restrict__ qhi, unsigned short* __restrict__ qlo,
    unsigned short* __restrict__ w1hi, unsigned short* __restrict__ w1lo,
    unsigned short* __restrict__ w3hi, unsigned short* __restrict__ w3lo,
    int* __restrict__ counts, int* __restrict__ ambig_cnt)
{
    const int b = blockIdx.x, t = threadIdx.x;
    if (b == 0) {
        if (t < NEXP) counts[t] = 0;
        if (t == NEXP) ambig_cnt[0] = 0;
    }
    const float* src; unsigned short *hi, *lo; int i;
    if (b < 8192)      { src = q;  hi = qhi;  lo = qlo;  i = b * 256 + t; }
    else if (b < 8704) { src = w1; hi = w1hi; lo = w1lo; i = (b - 8192) * 256 + t; }
    else               { src = w3; hi = w3hi; lo = w3lo; i = (b - 8704) * 256 + t; }
    float4 v = ((const float4*)src)[i];
    ushort4 h, l;
    h.x = f2bf(v.x); l.x = f2bf(v.x - bf2f(h.x));
    h.y = f2bf(v.y); l.y = f2bf(v.y - bf2f(h.y));
    h.z = f2bf(v.z); l.z = f2bf(v.z - bf2f(h.z));
    h.w = f2bf(v.w); l.w = f2bf(v.w - bf2f(h.w));
    ((ushort4*)hi)[i] = h;
    ((ushort4*)lo)[i] = l;
}

// fused plain conversion: exp_w1 (8192 blocks), exp_w2 (8192 blocks)
__global__ __launch_bounds__(256) void cvtB_kernel(
    const float* __restrict__ ew1, const float* __restrict__ ew2,
    unsigned short* __restrict__ d1, unsigned short* __restrict__ d2)
{
    const int b = blockIdx.x, t = threadIdx.x;
    const float* src; unsigned short* dst; int i;
    if (b < 8192) { src = ew1; dst = d1; i = b * 256 + t; }
    else          { src = ew2; dst = d2; i = (b - 8192) * 256 + t; }
    float4 v = ((const float4*)src)[i];
    ushort4 h;
    h.x = f2bf(v.x); h.y = f2bf(v.y); h.z = f2bf(v.z); h.w = f2bf(v.w);
    ((ushort4*)dst)[i] = h;
}

// ---- gating GEMM1 (split 3-term): x1 = relu(q @ w1^T + b1), stored hi/lo ----
// Triple-buffered counted-vmcnt pipeline (T3/T4-lite): loads for tile k+2 stay in
// flight across a raw s_barrier; each wave waits vmcnt(6) for the tile it reads.
// 128x64 tile, BK=32, 4 waves. grid (64, 8), block 256. LDS 72KB -> 2 blocks/CU.
__global__ __launch_bounds__(256) void g1_kernel(
    const unsigned short* __restrict__ qhi, const unsigned short* __restrict__ qlo,
    const unsigned short* __restrict__ w1hi, const unsigned short* __restrict__ w1lo,
    const float* __restrict__ b1,
    unsigned short* __restrict__ x1hi, unsigned short* __restrict__ x1lo)
{
    __shared__ unsigned short Ah[3][128][32];
    __shared__ unsigned short Al[3][128][32];
    __shared__ unsigned short Bh[3][64][32];
    __shared__ unsigned short Bl[3][64][32];

    const int t = threadIdx.x, w = t >> 6, lane = t & 63;
    const int quad = lane >> 4, l16 = lane & 15;
    const int rowA0 = blockIdx.x * 128;
    const int colB0 = blockIdx.y * 64;
    const int rl = lane >> 2, sl = lane & 3;   // staging: 16 rows x 4 slots per 1KB chunk

    const unsigned short* gsrc[6];
    unsigned short* lbase[6];
    int bstr[6];
    #pragma unroll
    for (int j = 0; j < 6; ++j) {
        int c = w + j * 4;
        int rloc; const unsigned short* s; unsigned short* d; int str;
        if (c < 8)       { rloc = c * 16 + rl;        s = qhi  + (size_t)(rowA0 + rloc) * H; d = &Ah[0][c * 16][0];        str = 128 * 32; }
        else if (c < 16) { rloc = (c - 8) * 16 + rl;  s = qlo  + (size_t)(rowA0 + rloc) * H; d = &Al[0][(c - 8) * 16][0];  str = 128 * 32; }
        else if (c < 20) { rloc = (c - 16) * 16 + rl; s = w1hi + (size_t)(colB0 + rloc) * H; d = &Bh[0][(c - 16) * 16][0]; str = 64 * 32; }
        else             { rloc = (c - 20) * 16 + rl; s = w1lo + (size_t)(colB0 + rloc) * H; d = &Bl[0][(c - 20) * 16][0]; str = 64 * 32; }
        int f = (rloc & 3) ^ ((rloc >> 2) & 3);
        gsrc[j]  = s + (sl ^ f) * 8;   // pre-swizzled k-slot in the source
        lbase[j] = d;
        bstr[j]  = str;
    }

    const f4 z4 = {0.f, 0.f, 0.f, 0.f};
    f4 acc[2][4] = {{z4, z4, z4, z4}, {z4, z4, z4, z4}};
    const int sw = (quad ^ (l16 & 3) ^ (l16 >> 2)) * 8;
    const int ra0 = w * 32 + l16, ra1 = ra0 + 16;

    auto STAGE = [&](int buf, int kt) {
        #pragma unroll
        for (int j = 0; j < 6; ++j)
            gld16(gsrc[j] + kt * 32, lbase[j] + buf * bstr[j]);
    };
    auto COMPUTE = [&](int buf) {
        bfrag ah0 = *(const bfrag*)&Ah[buf][ra0][sw];
        bfrag al0 = *(const bfrag*)&Al[buf][ra0][sw];
        bfrag ah1 = *(const bfrag*)&Ah[buf][ra1][sw];
        bfrag al1 = *(const bfrag*)&Al[buf][ra1][sw];
        #pragma unroll
        for (int cb = 0; cb < 4; ++cb) {
            bfrag bh = *(const bfrag*)&Bh[buf][cb * 16 + l16][sw];
            bfrag bl = *(const bfrag*)&Bl[buf][cb * 16 + l16][sw];
            acc[0][cb] = MF(al0, bh, MF(ah0, bl, MF(ah0, bh, acc[0][cb])));
            acc[1][cb] = MF(al1, bh, MF(ah1, bl, MF(ah1, bh, acc[1][cb])));
        }
    };

    STAGE(0, 0);
    STAGE(1, 1);
    for (int kt = 0; kt < 32; ++kt) {
        // wait: tile kt staged (newest 6 outstanding = tile kt+2's loads may remain)
        if (kt < 31) asm volatile("s_waitcnt vmcnt(6)" ::: "memory");
        else         asm volatile("s_waitcnt vmcnt(0)" ::: "memory");
        __builtin_amdgcn_s_barrier();   // all waves: tile kt ready AND compute(kt-1) done
        if (kt < 30) STAGE((kt + 2) % 3, kt + 2);   // safe: buf (kt-1)%3 no longer read
        COMPUTE(kt % 3);
    }

    const int row0 = rowA0 + w * 32;
    #pragma unroll
    for (int cb = 0; cb < 4; ++cb) {
        int col = colB0 + cb * 16 + l16;
        float bias = b1[col];
        #pragma unroll
        for (int rb = 0; rb < 2; ++rb)
            #pragma unroll
            for (int i = 0; i < 4; ++i) {
                int row = rb * 16 + quad * 4 + i;
                float v = fmaxf(acc[rb][cb][i] + bias, 0.f);
                unsigned short hh = f2bf(v);
                size_t idx = (size_t)(row0 + row) * HH + col;
                x1hi[idx] = hh;
                x1lo[idx] = f2bf(v - bf2f(hh));
            }
    }
}

// ---- logits (split 3-term) + argmax + gate + counts + ambiguity flag ----
__global__ __launch_bounds__(256) void logits_kernel(
    const unsigned short* __restrict__ x1hi, const unsigned short* __restrict__ x1lo,
    const unsigned short* __restrict__ w3hi, const unsigned short* __restrict__ w3lo,
    const float* __restrict__ b3,
    int* __restrict__ top1, float* __restrict__ gval, int* __restrict__ counts,
    int* __restrict__ ambig_rows, int* __restrict__ ambig_cnt)
{
    __shared__ float lgp[4][32][NEXP];
    const int t = threadIdx.x, wave = t >> 6, lane = t & 63;
    const int quad = lane >> 4, l16 = lane & 15;
    const int row0 = blockIdx.x * 32;
    const f4 z4 = {0.f, 0.f, 0.f, 0.f};

    f4 l0 = z4, l1 = z4;
    const size_t ar0 = (size_t)(row0 + l16) * HH + quad * 8;
    const size_t ar1 = ar0 + (size_t)16 * HH;
    const size_t br = (size_t)l16 * HH + quad * 8;
    #pragma unroll
    for (int ks = 0; ks < 4; ++ks) {
        int kk = wave * 128 + ks * 32;
        bfrag ah0 = *(const bfrag*)(x1hi + ar0 + kk);
        bfrag al0 = *(const bfrag*)(x1lo + ar0 + kk);
        bfrag ah1 = *(const bfrag*)(x1hi + ar1 + kk);
        bfrag al1 = *(const bfrag*)(x1lo + ar1 + kk);
        bfrag bh  = *(const bfrag*)(w3hi + br + kk);
        bfrag bl  = *(const bfrag*)(w3lo + br + kk);
        l0 = MF(al0, bh, MF(ah0, bl, MF(ah0, bh, l0)));
        l1 = MF(al1, bh, MF(ah1, bl, MF(ah1, bh, l1)));
    }
    #pragma unroll
    for (int i = 0; i < 4; ++i) {
        lgp[wave][quad * 4 + i][l16] = l0[i];
        lgp[wave][16 + quad * 4 + i][l16] = l1[i];
    }
    __syncthreads();

    if (t < 32) {
        float lg[NEXP];
        #pragma unroll
        for (int m = 0; m < NEXP; ++m)
            lg[m] = lgp[0][t][m] + lgp[1][t][m] + lgp[2][t][m] + lgp[3][t][m] + b3[m];
        float best = lg[0], second = -3.4e38f; int bi = 0;
        #pragma unroll
        for (int m = 1; m < NEXP; ++m) {
            float v = lg[m];
            if (v > best) { second = best; best = v; bi = m; }
            else if (v > second) second = v;
        }
        float se = 0.f;
        #pragma unroll
        for (int m = 0; m < NEXP; ++m) se += expf(lg[m] - best);
        int grow = row0 + t;
        top1[grow] = bi;
        gval[grow] = 1.f / se;
        atomicAdd(&counts[bi], 1);
        if (best - second < AMBIG_THR) {
            int pos = atomicAdd(ambig_cnt, 1);
            if (pos < NB) ambig_rows[pos] = grow;
        }
    }
}

// ---- exact fp32 x1 recompute for ambiguous rows, column-parallel ----
// grid 256 = 32 row-slots x 8 column-chunks (64 cols each); x1buf is fp32 [nn][HH].
__global__ __launch_bounds__(256) void fixup1_kernel(
    const float* __restrict__ q, const float* __restrict__ w1, const float* __restrict__ b1,
    const int* __restrict__ ambig_rows, const int* __restrict__ ambig_cnt,
    float* __restrict__ x1buf)
{
    __shared__ __align__(16) float qrow[H];
    const int t = threadIdx.x, wv = t >> 6, ln = t & 63;
    const int chunk = blockIdx.x & 7;        // 8 chunks of 64 columns
    const int slot  = blockIdx.x >> 3;       // 32 row slots
    const int base  = chunk * 64;
    int nn = *ambig_cnt; if (nn > NB) nn = NB;
    for (int ii = slot; ii < nn; ii += 32) {
        int row = ambig_rows[ii];
        ((float4*)qrow)[t] = ((const float4*)(q + (size_t)row * H))[t];
        __syncthreads();
        for (int c = base + wv * 2; c < base + 64; c += 8) {
            const float4* w0 = (const float4*)(w1 + (size_t)c * H);
            const float4* w1r = (const float4*)(w1 + (size_t)(c + 1) * H);
            const float4* qv = (const float4*)qrow;
            float s0 = 0.f, s1 = 0.f;
            #pragma unroll
            for (int j = 0; j < 4; ++j) {
                float4 a = qv[j * 64 + ln];
                float4 b0 = w0[j * 64 + ln];
                float4 b1v = w1r[j * 64 + ln];
                s0 += a.x * b0.x + a.y * b0.y + a.z * b0.z + a.w * b0.w;
                s1 += a.x * b1v.x + a.y * b1v.y + a.z * b1v.z + a.w * b1v.w;
            }
            #pragma unroll
            for (int off = 32; off; off >>= 1) {
                s0 += __shfl_xor(s0, off, 64);
                s1 += __shfl_xor(s1, off, 64);
            }
            if (ln == 0) {
                x1buf[(size_t)ii * HH + c]     = fmaxf(s0 + b1[c], 0.f);
                x1buf[(size_t)ii * HH + c + 1] = fmaxf(s1 + b1[c + 1], 0.f);
            }
        }
        __syncthreads();
    }
}

// ---- logits from exact x1 + top1/gval/counts update (one block per ambig row) ----
__global__ __launch_bounds__(256) void fixup2_kernel(
    const float* __restrict__ x1buf,
    const float* __restrict__ w3, const float* __restrict__ b3,
    const int* __restrict__ ambig_rows, const int* __restrict__ ambig_cnt,
    int* __restrict__ top1, float* __restrict__ gval, int* __restrict__ counts)
{
    __shared__ float lgs[NEXP];
    const int t = threadIdx.x, wv = t >> 6, ln = t & 63;
    int nn = *ambig_cnt; if (nn > NB) nn = NB;
    for (int ii = blockIdx.x; ii < nn; ii += gridDim.x) {
        int row = ambig_rows[ii];
        const float4* xv = (const float4*)(x1buf + (size_t)ii * HH);
        for (int m = wv; m < NEXP; m += 4) {
            const float4* wr = (const float4*)(w3 + (size_t)m * HH);
            float s = 0.f;
            #pragma unroll
            for (int j = 0; j < 2; ++j) {
                float4 a = xv[j * 64 + ln];
                float4 b = wr[j * 64 + ln];
                s += a.x * b.x + a.y * b.y + a.z * b.z + a.w * b.w;
            }
            #pragma unroll
            for (int off = 32; off; off >>= 1) s += __shfl_xor(s, off, 64);
            if (ln == 0) lgs[m] = s + b3[m];
        }
        __syncthreads();
        if (t == 0) {
            float best = lgs[0]; int bi = 0;
            #pragma unroll
            for (int m = 1; m < NEXP; ++m) if (lgs[m] > best) { best = lgs[m]; bi = m; }
            float se = 0.f;
            #pragma unroll
            for (int m = 0; m < NEXP; ++m) se += expf(lgs[m] - best);
            int old = top1[row];
            if (bi != old) {
                atomicSub(&counts[old], 1);
                atomicAdd(&counts[bi], 1);
                top1[row] = bi;
            }
            gval[row] = 1.f / se;
        }
        __syncthreads();
    }
}

// fused offsets + tile-map + scatter (single block; LDS atomics)
__global__ __launch_bounds__(256) void osc_kernel(
    const int* __restrict__ counts,
    int* __restrict__ tm_e, int* __restrict__ tm_p, int* __restrict__ tm_end,
    const int* __restrict__ top1, int* __restrict__ brows)
{
    __shared__ int sbpos[NEXP];
    const int t = threadIdx.x;
    if (t == 0) {
        int run = 0, tile = 0;
        for (int e = 0; e < NEXP; ++e) {
            sbpos[e] = run;
            int beg = run, end = run + counts[e];
            for (int p = beg; p < end; p += 128) {
                tm_e[tile] = e; tm_p[tile] = p; tm_end[tile] = end; ++tile;
            }
            run = end;
        }
        for (; tile < NT128; ++tile) tm_e[tile] = -1;
    }
    __syncthreads();
    for (int i = t; i < NB; i += 256) {
        int e = top1[i];
        int pos = atomicAdd(&sbpos[e], 1);
        brows[pos] = i;
    }
}

// ---- expert GEMM1: h[pos][512] = relu(q[brows[pos]] @ w1[e]^T + b1[e]) ----
// Triple-buffered counted-vmcnt; 128x64 tile, BK=32, 4 waves. grid (NT128, 8).
__global__ __launch_bounds__(256) void exp1_kernel(
    const unsigned short* __restrict__ qb, const unsigned short* __restrict__ ew1b,
    const float* __restrict__ eb1,
    const int* __restrict__ tm_e, const int* __restrict__ tm_p, const int* __restrict__ tm_end,
    const int* __restrict__ brows, unsigned short* __restrict__ h)
{
    const int e = tm_e[blockIdx.x];
    if (e < 0) return;                       // block-uniform: safe with barriers
    const int p0 = tm_p[blockIdx.x], end = tm_end[blockIdx.x];

    __shared__ unsigned short A[3][128][32];
    __shared__ unsigned short B[3][64][32];

    const int t = threadIdx.x, w = t >> 6, lane = t & 63;
    const int quad = lane >> 4, l16 = lane & 15;
    const int c0 = blockIdx.y * 64;
    const unsigned short* w1p = ew1b + (size_t)e * HH * H;
    const int rl = lane >> 2, sl = lane & 3;

    const unsigned short* gsrc[3];
    unsigned short* lbase[3];
    int bstr[3];
    #pragma unroll
    for (int j = 0; j < 3; ++j) {
        int c = w + j * 4;
        int rloc; const unsigned short* s; unsigned short* d; int str;
        if (c < 8) {
            rloc = c * 16 + rl;
            int pa = p0 + rloc; if (pa >= end) pa = end - 1;   // ragged tail: duplicate last row
            s = qb + (size_t)brows[pa] * H;
            d = &A[0][c * 16][0]; str = 128 * 32;
        } else {
            rloc = (c - 8) * 16 + rl;
            s = w1p + (size_t)(c0 + rloc) * H;
            d = &B[0][(c - 8) * 16][0]; str = 64 * 32;
        }
        int f = (rloc & 3) ^ ((rloc >> 2) & 3);
        gsrc[j]  = s + (sl ^ f) * 8;
        lbase[j] = d;
        bstr[j]  = str;
    }

    const f4 z4 = {0.f, 0.f, 0.f, 0.f};
    f4 acc[2][4] = {{z4, z4, z4, z4}, {z4, z4, z4, z4}};
    const int sw = (quad ^ (l16 & 3) ^ (l16 >> 2)) * 8;
    const int ra0 = w * 32 + l16, ra1 = ra0 + 16;

    auto STAGE = [&](int buf, int kt) {
        #pragma unroll
        for (int j = 0; j < 3; ++j)
            gld16(gsrc[j] + kt * 32, lbase[j] + buf * bstr[j]);
    };
    auto COMPUTE = [&](int buf) {
        bfrag a0 = *(const bfrag*)&A[buf][ra0][sw];
        bfrag a1 = *(const bfrag*)&A[buf][ra1][sw];
        #pragma unroll
        for (int cb = 0; cb < 4; ++cb) {
            bfrag bb = *(const bfrag*)&B[buf][cb * 16 + l16][sw];
            acc[0][cb] = MF(a0, bb, acc[0][cb]);
            acc[1][cb] = MF(a1, bb, acc[1][cb]);
        }
    };

    STAGE(0, 0);
    STAGE(1, 1);
    for (int kt = 0; kt < 32; ++kt) {
        if (kt < 31) asm volatile("s_waitcnt vmcnt(3)" ::: "memory");
        else         asm volatile("s_waitcnt vmcnt(0)" ::: "memory");
        __builtin_amdgcn_s_barrier();
        if (kt < 30) STAGE((kt + 2) % 3, kt + 2);
        COMPUTE(kt % 3);
    }

    const int prow0 = p0 + w * 32;
    #pragma unroll
    for (int cb = 0; cb < 4; ++cb) {
        int col = c0 + cb * 16 + l16;
        float bias = eb1[e * HH + col];
        #pragma unroll
        for (int rb = 0; rb < 2; ++rb)
            #pragma unroll
            for (int i = 0; i < 4; ++i) {
                int row = rb * 16 + quad * 4 + i;
                if (prow0 + row < end)
                    h[(size_t)(prow0 + row) * HH + col] = f2bf(fmaxf(acc[rb][cb][i] + bias, 0.f));
            }
    }
}

// ---- expert GEMM2: v = h @ w2[e]^T + b2[e]; psum[row][cg] = partial sum v^2 ----
// Triple-buffered counted-vmcnt; 128x64 tile, BK=32, 4 waves. grid (NT128, 16).
__global__ __launch_bounds__(256) void exp2_kernel(
    const unsigned short* __restrict__ h, const unsigned short* __restrict__ ew2b,
    const float* __restrict__ eb2,
    const int* __restrict__ tm_e, const int* __restrict__ tm_p, const int* __restrict__ tm_end,
    const int* __restrict__ brows,
    float* __restrict__ vout, float* __restrict__ psum)
{
    const int e = tm_e[blockIdx.x];
    if (e < 0) return;
    const int p0 = tm_p[blockIdx.x], end = tm_end[blockIdx.x];

    __shared__ unsigned short A[3][128][32];
    __shared__ unsigned short B[3][64][32];

    const int t = threadIdx.x, w = t >> 6, lane = t & 63;
    const int quad = lane >> 4, l16 = lane & 15;
    const int cg = blockIdx.y;
    const int c0 = cg * 64;
    const unsigned short* w2p = ew2b + (size_t)e * H * HH;
    const int rl = lane >> 2, sl = lane & 3;

    const unsigned short* gsrc[3];
    unsigned short* lbase[3];
    int bstr[3];
    #pragma unroll
    for (int j = 0; j < 3; ++j) {
        int c = w + j * 4;
        int rloc; const unsigned short* s; unsigned short* d; int str;
        if (c < 8) {
            rloc = c * 16 + rl;
            int pa = p0 + rloc; if (pa >= end) pa = end - 1;
            s = h + (size_t)pa * HH;
            d = &A[0][c * 16][0]; str = 128 * 32;
        } else {
            rloc = (c - 8) * 16 + rl;
            s = w2p + (size_t)(c0 + rloc) * HH;
            d = &B[0][(c - 8) * 16][0]; str = 64 * 32;
        }
        int f = (rloc & 3) ^ ((rloc >> 2) & 3);
        gsrc[j]  = s + (sl ^ f) * 8;
        lbase[j] = d;
        bstr[j]  = str;
    }

    const f4 z4 = {0.f, 0.f, 0.f, 0.f};
    f4 acc[2][4] = {{z4, z4, z4, z4}, {z4, z4, z4, z4}};
    const int sw = (quad ^ (l16 & 3) ^ (l16 >> 2)) * 8;
    const int ra0 = w * 32 + l16, ra1 = ra0 + 16;

    auto STAGE = [&](int buf, int kt) {
        #pragma unroll
        for (int j = 0; j < 3; ++j)
            gld16(gsrc[j] + kt * 32, lbase[j] + buf * bstr[j]);
    };
    auto COMPUTE = [&](int buf) {
        bfrag a0 = *(const bfrag*)&A[buf][ra0][sw];
        bfrag a1 = *(const bfrag*)&A[buf][ra1][sw];
        #pragma unroll
        for (int cb = 0; cb < 4; ++cb) {
            bfrag bb = *(const bfrag*)&B[buf][cb * 16 + l16][sw];
            acc[0][cb] = MF(a0, bb, acc[0][cb]);
            acc[1][cb] = MF(a1, bb, acc[1][cb]);
        }
    };

    STAGE(0, 0);
    STAGE(1, 1);
    for (int kt = 0; kt < 16; ++kt) {
        if (kt < 15) asm volatile("s_waitcnt vmcnt(3)" ::: "memory");
        else         asm volatile("s_waitcnt vmcnt(0)" ::: "memory");
        __builtin_amdgcn_s_barrier();
        if (kt < 14) STAGE((kt + 2) % 3, kt + 2);
        COMPUTE(kt % 3);
    }

    // bias + v-write + per-row sum(v^2); wave w owns positions p0+w*32 .. +31
    const int pw0 = p0 + w * 32;
    float rs0[4] = {0.f, 0.f, 0.f, 0.f}, rs1[4] = {0.f, 0.f, 0.f, 0.f};
    #pragma unroll
    for (int i = 0; i < 4; ++i) {
        int row0i = quad * 4 + i, row1i = 16 + quad * 4 + i;
        int g0 = pw0 + row0i; if (g0 >= end) g0 = end - 1;
        int g1 = pw0 + row1i; if (g1 >= end) g1 = end - 1;
        int gr0 = brows[g0], gr1 = brows[g1];
        #pragma unroll
        for (int cb = 0; cb < 4; ++cb) {
            int col = c0 + cb * 16 + l16;
            float bias = eb2[e * H + col];
            float v0 = acc[0][cb][i] + bias;
            float v1 = acc[1][cb][i] + bias;
            vout[(size_t)gr0 * H + col] = v0;
            vout[(size_t)gr1 * H + col] = v1;
            rs0[i] += v0 * v0;
            rs1[i] += v1 * v1;
        }
    }
    #pragma unroll
    for (int i = 0; i < 4; ++i) {
        float s0 = rs0[i], s1 = rs1[i];
        #pragma unroll
        for (int off = 8; off; off >>= 1) {
            s0 += __shfl_xor(s0, off, 16);
            s1 += __shfl_xor(s1, off, 16);
        }
        if (l16 == 0) {
            int g0 = pw0 + quad * 4 + i;      if (g0 >= end) g0 = end - 1;
            int g1 = pw0 + 16 + quad * 4 + i; if (g1 >= end) g1 = end - 1;
            psum[(size_t)brows[g0] * 16 + cg] = s0;
            psum[(size_t)brows[g1] * 16 + cg] = s1;
        }
    }
}

// out = v * scale + q ; scale computed inline from psum (one block per row)
__global__ __launch_bounds__(256) void finalize_kernel(
    float* __restrict__ out, const float* __restrict__ q,
    const float* __restrict__ psum, const float* __restrict__ gval)
{
    const int row = blockIdx.x, t = threadIdx.x;
    float s = 0.f;
    #pragma unroll
    for (int j = 0; j < 16; ++j) s += psum[(size_t)row * 16 + j];
    float g = gval[row];
    float sc = g / fmaxf(g * sqrtf(s), 1e-6f);
    size_t i = (size_t)row * 256 + t;
    float4 v = ((const float4*)out)[i];
    float4 qq = ((const float4*)q)[i];
    float4 o;
    o.x = v.x * sc + qq.x;
    o.y = v.y * sc + qq.y;
    o.z = v.z * sc + qq.z;
    o.w = v.w * sc + qq.w;
    ((float4*)out)[i] = o;
}

extern "C" void kernel_launch(void* const* d_in, const int* in_sizes, int n_in,
                              void* d_out, int out_size, void* d_ws, size_t ws_size,
                              hipStream_t stream) {
    const float* q      = (const float*)d_in[0];
    const float* cls1_w = (const float*)d_in[1];
    const float* cls1_b = (const float*)d_in[2];
    const float* cls3_w = (const float*)d_in[3];
    const float* cls3_b = (const float*)d_in[4];
    const float* exp_w1 = (const float*)d_in[5];
    const float* exp_b1 = (const float*)d_in[6];
    const float* exp_w2 = (const float*)d_in[7];
    const float* exp_b2 = (const float*)d_in[8];
    float* out = (float*)d_out;

    // ---- workspace layout (~62 MB), lifetime-based aliasing ----
    char* w = (char*)d_ws;
    float* psum   = (float*)w;              w += (size_t)NB * 16 * 4;
    float* gvalp  = (float*)w;              w += (size_t)NB * 4;
    int* top1     = (int*)w;                w += (size_t)NB * 4;
    int* brows    = (int*)w;                w += (size_t)NB * 4;
    int* ambig_rows = (int*)w;              w += (size_t)NB * 4;
    int* counts   = (int*)w;                w += 16 * 4;
    int* offsets  = (int*)w;                w += 16 * 4;   // unused (kept for layout stability)
    int* bpos     = (int*)w;                w += 16 * 4;   // unused
    int* ambig_cnt = (int*)w;               w += 4 * 4;
    int* tm_e     = (int*)w;                w += NT128 * 4;
    int* tm_p     = (int*)w;                w += NT128 * 4;
    int* tm_end   = (int*)w;                w += NT128 * 4;
    w = (char*)(((size_t)w + 15) & ~(size_t)15);
    unsigned short* qhi  = (unsigned short*)w;  w += (size_t)NB * H * 2;   // lives whole pipeline
    unsigned short* qlo  = (unsigned short*)w;  w += (size_t)NB * H * 2;   // dead after g1 -> ew2b
    unsigned short* x1hi = (unsigned short*)w;                              // dead after logits
    unsigned short* x1lo = x1hi + (size_t)NB * HH;  w += (size_t)NB * HH * 2 * 2;  // -> x1buf -> ew1b
    unsigned short* hbuf = (unsigned short*)w;  w += (size_t)NB * HH * 2;
    unsigned short* w1hi = (unsigned short*)w;  w += (size_t)HH * H * 2;
    unsigned short* w1lo = (unsigned short*)w;  w += (size_t)HH * H * 2;
    unsigned short* w3hi = (unsigned short*)w;  w += (size_t)NEXP * HH * 2;
    unsigned short* w3lo = (unsigned short*)w;  w += (size_t)NEXP * HH * 2;
    unsigned short* ew1b = x1hi;   // reused after logits+fixup
    unsigned short* ew2b = qlo;    // reused after g1
    float* x1buf = (float*)x1hi;   // fp32 [NB][HH] alias: dead x1hi/x1lo = 16 MB, used fixup1->fixup2
    (void)offsets; (void)bpos;

    cvtA_kernel<<<8712, 256, 0, stream>>>(q, cls1_w, cls3_w, qhi, qlo, w1hi, w1lo,
                                          w3hi, w3lo, counts, ambig_cnt);
    g1_kernel<<<dim3(NB / 128, 8), 256, 0, stream>>>(qhi, qlo, w1hi, w1lo, cls1_b, x1hi, x1lo);
    logits_kernel<<<NB / 32, 256, 0, stream>>>(x1hi, x1lo, w3hi, w3lo, cls3_b,
                                               top1, gvalp, counts, ambig_rows, ambig_cnt);
    fixup1_kernel<<<256, 256, 0, stream>>>(q, cls1_w, cls1_b, ambig_rows, ambig_cnt, x1buf);
    fixup2_kernel<<<64, 256, 0, stream>>>(x1buf, cls3_w, cls3_b, ambig_rows, ambig_cnt,
                                          top1, gvalp, counts);
    cvtB_kernel<<<16384, 256, 0, stream>>>(exp_w1, exp_w2, ew1b, ew2b);
    osc_kernel<<<1, 256, 0, stream>>>(counts, tm_e, tm_p, tm_end, top1, brows);
    exp1_kernel<<<dim3(NT128, 8), 256, 0, stream>>>(qhi, ew1b, exp_b1,
                                                    tm_e, tm_p, tm_end, brows, hbuf);
    exp2_kernel<<<dim3(NT128, 16), 256, 0, stream>>>(hbuf, ew2b, exp_b2,
                                                     tm_e, tm_p, tm_end, brows, out, psum);
    finalize_kernel<<<NB, 256, 0, stream>>>(out, q, psum, gvalp);
}